// Round 1
// baseline (13865.889 us; speedup 1.0000x reference)
//
#include <hip/hip_runtime.h>
#include <math.h>

// ---- problem constants ----
constexpr int Bsz = 32, Cch = 3, IMGS = 224, PP = 16;
constexpr int E = 768, HEADS = 8, Lnum = 6, NC = 1000;
constexpr int HD = 96;            // E / HEADS
constexpr int NP = 196;           // (224/16)^2
constexpr int Nn = 197;           // NP + 1 (cls)
constexpr int FF = 3072;          // 4*E
constexpr float SCALE = 0.10206207261596575f;  // 96^-0.5
constexpr float EPSc  = 1e-5f;

// =====================================================================
// im2col: A[(b*196+p), (c*256+i*16+j)] = x[b, c, ph*16+i, pw*16+j]
// =====================================================================
__global__ void im2col_k(const float* __restrict__ x, float* __restrict__ A) {
    int idx = blockIdx.x * 256 + threadIdx.x;
    if (idx >= NP * Bsz * (Cch * PP * PP)) return;
    int col = idx % 768;
    int row = idx / 768;
    int b  = row / NP;
    int p  = row % NP;
    int hh = p / 14, ww = p % 14;
    int c  = col / 256;
    int rem = col % 256;
    int i = rem / 16, j = rem % 16;
    A[idx] = x[(((size_t)b * Cch + c) * IMGS + hh * 16 + i) * IMGS + ww * 16 + j];
}

// =====================================================================
// generic GEMM: out[m,n] = act(bias[n] + sum_k A[m,k] * W[n,k])
// W is [N,K] row-major (torch Linear weight convention). K % 16 == 0.
// 64x64 tile, 16x16 threads, 4x4 per thread.
// ACT: 0 = none, 1 = exact gelu
// =====================================================================
template <int ACT>
__global__ void gemm_k(const float* __restrict__ A, const float* __restrict__ W,
                       const float* __restrict__ bias, float* __restrict__ out,
                       int M, int N, int K) {
    __shared__ float As[16][65];  // [k][m], padded
    __shared__ float Bs[16][65];  // [k][n], padded
    const int tx = threadIdx.x, ty = threadIdx.y;
    const int tid = ty * 16 + tx;
    const int m0 = blockIdx.x * 64, n0 = blockIdx.y * 64;
    float acc[4][4] = {};
    for (int k0 = 0; k0 < K; k0 += 16) {
#pragma unroll
        for (int i = 0; i < 4; i++) {
            int e = tid + i * 256;
            int m = e >> 4, kk = e & 15;
            int gm = m0 + m;
            As[kk][m] = (gm < M) ? A[(size_t)gm * K + k0 + kk] : 0.f;
        }
#pragma unroll
        for (int i = 0; i < 4; i++) {
            int e = tid + i * 256;
            int n = e >> 4, kk = e & 15;
            int gn = n0 + n;
            Bs[kk][n] = (gn < N) ? W[(size_t)gn * K + k0 + kk] : 0.f;
        }
        __syncthreads();
#pragma unroll
        for (int kk = 0; kk < 16; kk++) {
            float a[4], bv[4];
#pragma unroll
            for (int i = 0; i < 4; i++) a[i] = As[kk][ty + i * 16];
#pragma unroll
            for (int j = 0; j < 4; j++) bv[j] = Bs[kk][tx + j * 16];
#pragma unroll
            for (int i = 0; i < 4; i++)
#pragma unroll
                for (int j = 0; j < 4; j++) acc[i][j] += a[i] * bv[j];
        }
        __syncthreads();
    }
#pragma unroll
    for (int i = 0; i < 4; i++) {
        int gm = m0 + ty + i * 16;
        if (gm >= M) continue;
#pragma unroll
        for (int j = 0; j < 4; j++) {
            int gn = n0 + tx + j * 16;
            if (gn >= N) continue;
            float v = acc[i][j] + bias[gn];
            if (ACT == 1) v = 0.5f * v * (1.0f + erff(v * 0.70710678118654752f));
            out[(size_t)gm * N + gn] = v;
        }
    }
}

// =====================================================================
// assemble: X[b,n,e] = (n==0 ? cls[e] : patch[(b,n-1),e]) + pos[n,e]
// =====================================================================
__global__ void assemble_k(const float* __restrict__ ptmp, const float* __restrict__ cls,
                           const float* __restrict__ pos, float* __restrict__ X) {
    int idx = blockIdx.x * 256 + threadIdx.x;
    if (idx >= Bsz * Nn * E) return;
    int e = idx % E;
    int r = idx / E;
    int n = r % Nn, b = r / Nn;
    float v = (n == 0) ? cls[e] : ptmp[((size_t)b * NP + (n - 1)) * E + e];
    X[idx] = v + pos[(size_t)n * E + e];
}

// =====================================================================
// QK^T: sim[b,h,i,j] = sum_d q[b,i,h,d] * k[b,j,h,d]
// q at qkv[(b*197+i)*2304 + h*96 + d], k at +768
// =====================================================================
__global__ void qk_k(const float* __restrict__ qkv, float* __restrict__ sim) {
    __shared__ float qs[16][97];
    __shared__ float ks[16][97];
    const int bh = blockIdx.z;
    const int b = bh >> 3, h = bh & 7;
    const int i0 = blockIdx.y * 16, j0 = blockIdx.x * 16;
    const int tid = threadIdx.y * 16 + threadIdx.x;
    for (int e = tid; e < 16 * 96; e += 256) {
        int r = e / 96, d = e % 96;
        int gi = i0 + r, gj = j0 + r;
        qs[r][d] = (gi < Nn) ? qkv[((size_t)(b * Nn + gi)) * 2304 + h * 96 + d] : 0.f;
        ks[r][d] = (gj < Nn) ? qkv[((size_t)(b * Nn + gj)) * 2304 + 768 + h * 96 + d] : 0.f;
    }
    __syncthreads();
    const int ii = threadIdx.y, jj = threadIdx.x;
    float acc = 0.f;
#pragma unroll
    for (int d = 0; d < 96; d++) acc += qs[ii][d] * ks[jj][d];
    int gi = i0 + ii, gj = j0 + jj;
    if (gi < Nn && gj < Nn) sim[((size_t)bh * Nn + gi) * Nn + gj] = acc;
}

// =====================================================================
// softmax over last dim (197), then multiply by SCALE (scale AFTER softmax)
// one wave per row
// =====================================================================
__global__ void softmax_k(float* __restrict__ sim) {
    const size_t row = blockIdx.x;
    float* p = sim + row * Nn;
    const int lane = threadIdx.x;  // 64
    float vals[4];
    float vmax = -1e30f;
#pragma unroll
    for (int t = 0; t < 4; t++) {
        int j = lane + t * 64;
        vals[t] = (j < Nn) ? p[j] : -1e30f;
        vmax = fmaxf(vmax, vals[t]);
    }
    for (int off = 32; off > 0; off >>= 1) vmax = fmaxf(vmax, __shfl_down(vmax, off));
    vmax = __shfl(vmax, 0);
    float s = 0.f;
#pragma unroll
    for (int t = 0; t < 4; t++) {
        int j = lane + t * 64;
        float ev = (j < Nn) ? expf(vals[t] - vmax) : 0.f;
        vals[t] = ev;
        s += ev;
    }
    for (int off = 32; off > 0; off >>= 1) s += __shfl_down(s, off);
    s = __shfl(s, 0);
    float inv = SCALE / s;
#pragma unroll
    for (int t = 0; t < 4; t++) {
        int j = lane + t * 64;
        if (j < Nn) p[j] = vals[t] * inv;
    }
}

// =====================================================================
// P@V: att[b,i, h*96+d] = sum_j sim[b,h,i,j] * v[b,j,h,d]
// block: 192 threads -> d = t%96, iset = t/96 (2 half-tiles of 8 rows)
// =====================================================================
__global__ void av_k(const float* __restrict__ sim, const float* __restrict__ qkv,
                     float* __restrict__ att) {
    __shared__ float ps[16][17];
    __shared__ float vs[16][96];
    const int bh = blockIdx.y;
    const int b = bh >> 3, h = bh & 7;
    const int i0 = blockIdx.x * 16;
    const int t = threadIdx.x;  // 0..191
    const int d = t % 96, iset = t / 96;
    float acc[8] = {};
    for (int j0 = 0; j0 < Nn; j0 += 16) {
        for (int e = t; e < 256; e += 192) {
            int r = e / 16, cj = e % 16;
            int gi = i0 + r, gj = j0 + cj;
            ps[r][cj] = (gi < Nn && gj < Nn) ? sim[((size_t)bh * Nn + gi) * Nn + gj] : 0.f;
        }
        for (int e = t; e < 1536; e += 192) {
            int r = e / 96, dd = e % 96;
            int gj = j0 + r;
            vs[r][dd] = (gj < Nn) ? qkv[((size_t)(b * Nn + gj)) * 2304 + 1536 + h * 96 + dd] : 0.f;
        }
        __syncthreads();
#pragma unroll
        for (int jj = 0; jj < 16; jj++) {
            float vv = vs[jj][d];
#pragma unroll
            for (int r = 0; r < 8; r++) acc[r] += ps[iset * 8 + r][jj] * vv;
        }
        __syncthreads();
    }
#pragma unroll
    for (int r = 0; r < 8; r++) {
        int gi = i0 + iset * 8 + r;
        if (gi < Nn) att[((size_t)(b * Nn + gi)) * E + h * 96 + d] = acc[r];
    }
}

// =====================================================================
// x = LayerNorm(x + t) * g + b   (row of 768, one block of 256 per row)
// =====================================================================
__global__ void add_ln_k(float* __restrict__ X, const float* __restrict__ T,
                         const float* __restrict__ g, const float* __restrict__ bb) {
    const size_t row = blockIdx.x;
    float* xr = X + row * E;
    const float* tr = T + row * E;
    const int t = threadIdx.x;  // 256
    __shared__ float red[4];
    float v[3];
    float s = 0.f;
#pragma unroll
    for (int i = 0; i < 3; i++) {
        v[i] = xr[t + i * 256] + tr[t + i * 256];
        s += v[i];
    }
    for (int off = 32; off > 0; off >>= 1) s += __shfl_down(s, off);
    int wid = t >> 6, lane = t & 63;
    if (lane == 0) red[wid] = s;
    __syncthreads();
    if (t == 0) red[0] = red[0] + red[1] + red[2] + red[3];
    __syncthreads();
    float mean = red[0] / 768.f;
    __syncthreads();
    float s2 = 0.f;
#pragma unroll
    for (int i = 0; i < 3; i++) {
        float dl = v[i] - mean;
        s2 += dl * dl;
    }
    for (int off = 32; off > 0; off >>= 1) s2 += __shfl_down(s2, off);
    if (lane == 0) red[wid] = s2;
    __syncthreads();
    if (t == 0) red[0] = red[0] + red[1] + red[2] + red[3];
    __syncthreads();
    float rs = rsqrtf(red[0] / 768.f + EPSc);
#pragma unroll
    for (int i = 0; i < 3; i++) {
        int e = t + i * 256;
        xr[e] = (v[i] - mean) * rs * g[e] + bb[e];
    }
}

// =====================================================================
// mean-pool over N, LN, then head Linear -> out[b, 1000]
// one block (256 threads) per batch element
// =====================================================================
__global__ void pool_head_k(const float* __restrict__ X, const float* __restrict__ g,
                            const float* __restrict__ bb, const float* __restrict__ hw,
                            const float* __restrict__ hb, float* __restrict__ out) {
    __shared__ float pooled[768];
    __shared__ float red[4];
    const int b = blockIdx.x, t = threadIdx.x;
    float loc[3];
#pragma unroll
    for (int i = 0; i < 3; i++) {
        int e = t + i * 256;
        float s = 0.f;
        for (int n = 0; n < Nn; n++) s += X[((size_t)(b * Nn + n)) * E + e];
        loc[i] = s / (float)Nn;
    }
    float s = loc[0] + loc[1] + loc[2];
    for (int off = 32; off > 0; off >>= 1) s += __shfl_down(s, off);
    int wid = t >> 6, lane = t & 63;
    if (lane == 0) red[wid] = s;
    __syncthreads();
    if (t == 0) red[0] = red[0] + red[1] + red[2] + red[3];
    __syncthreads();
    float mean = red[0] / 768.f;
    __syncthreads();
    float s2 = 0.f;
#pragma unroll
    for (int i = 0; i < 3; i++) {
        float dl = loc[i] - mean;
        s2 += dl * dl;
    }
    for (int off = 32; off > 0; off >>= 1) s2 += __shfl_down(s2, off);
    if (lane == 0) red[wid] = s2;
    __syncthreads();
    if (t == 0) red[0] = red[0] + red[1] + red[2] + red[3];
    __syncthreads();
    float rs = rsqrtf(red[0] / 768.f + EPSc);
#pragma unroll
    for (int i = 0; i < 3; i++) {
        int e = t + i * 256;
        pooled[e] = (loc[i] - mean) * rs * g[e] + bb[e];
    }
    __syncthreads();
    for (int o = t; o < NC; o += 256) {
        float acc = hb[o];
        const float* wr = hw + (size_t)o * 768;
        for (int e = 0; e < 768; e++) acc += pooled[e] * wr[e];
        out[(size_t)b * NC + o] = acc;
    }
}

// =====================================================================
extern "C" void kernel_launch(void* const* d_in, const int* in_sizes, int n_in,
                              void* d_out, int out_size, void* d_ws, size_t ws_size,
                              hipStream_t stream) {
    const float* x        = (const float*)d_in[0];
    const float* conv_w   = (const float*)d_in[1];
    const float* conv_b   = (const float*)d_in[2];
    const float* cls_tok  = (const float*)d_in[3];
    const float* pos_emb  = (const float*)d_in[4];
    const float* qkv_w    = (const float*)d_in[5];
    const float* qkv_b    = (const float*)d_in[6];
    const float* proj_w   = (const float*)d_in[7];
    const float* proj_b   = (const float*)d_in[8];
    const float* ln1_g    = (const float*)d_in[9];
    const float* ln1_b    = (const float*)d_in[10];
    const float* mlp_w1   = (const float*)d_in[11];
    const float* mlp_b1   = (const float*)d_in[12];
    const float* mlp_w2   = (const float*)d_in[13];
    const float* mlp_b2   = (const float*)d_in[14];
    const float* ln2_g    = (const float*)d_in[15];
    const float* ln2_b    = (const float*)d_in[16];
    const float* hln_g    = (const float*)d_in[17];
    const float* hln_b    = (const float*)d_in[18];
    const float* head_w   = (const float*)d_in[19];
    const float* head_b   = (const float*)d_in[20];
    float* out = (float*)d_out;

    float* ws = (float*)d_ws;
    const size_t szX = (size_t)Bsz * Nn * E;           // 4,844,544
    const size_t szA = (size_t)Bsz * Nn * 3 * E;       // 14,533,632 (qkv)
    const size_t szS = (size_t)Bsz * HEADS * Nn * Nn;  // 9,935,104  (sim / proj tmp)
    const size_t szC = (size_t)Bsz * Nn * E;           // 4,844,544  (att / mlp2 out / patch tmp)
    float* X    = ws;
    float* Abuf = X + szX;
    float* Sbuf = Abuf + szA;
    float* Cbuf = Sbuf + szS;
    float* Hbuf = Abuf;  // [6304,3072] spans A..S (both dead during MLP)

    const int M = Bsz * Nn;  // 6304

    // ---- patch embed ----
    {
        int tot = Bsz * NP * 768;
        im2col_k<<<(tot + 255) / 256, 256, 0, stream>>>(x, Abuf);
        dim3 g((Bsz * NP + 63) / 64, 768 / 64);
        gemm_k<0><<<g, dim3(16, 16), 0, stream>>>(Abuf, conv_w, conv_b, Cbuf,
                                                  Bsz * NP, 768, 768);
        int tot2 = Bsz * Nn * E;
        assemble_k<<<(tot2 + 255) / 256, 256, 0, stream>>>(Cbuf, cls_tok, pos_emb, X);
    }

    // ---- transformer layers ----
    for (int l = 0; l < Lnum; l++) {
        const float* qw = qkv_w + (size_t)l * 3 * E * E;
        const float* qb = qkv_b + (size_t)l * 3 * E;
        const float* pw = proj_w + (size_t)l * E * E;
        const float* pb = proj_b + (size_t)l * E;
        const float* g1 = ln1_g + (size_t)l * E;
        const float* b1 = ln1_b + (size_t)l * E;
        const float* w1 = mlp_w1 + (size_t)l * FF * E;
        const float* bb1 = mlp_b1 + (size_t)l * FF;
        const float* w2 = mlp_w2 + (size_t)l * E * FF;
        const float* bb2 = mlp_b2 + (size_t)l * E;
        const float* g2 = ln2_g + (size_t)l * E;
        const float* b2 = ln2_b + (size_t)l * E;

        // qkv = X @ qw^T + qb  -> Abuf [6304, 2304]
        {
            dim3 g((M + 63) / 64, (3 * E) / 64);
            gemm_k<0><<<g, dim3(16, 16), 0, stream>>>(X, qw, qb, Abuf, M, 3 * E, E);
        }
        // sim = q @ k^T -> Sbuf
        {
            dim3 g((Nn + 15) / 16, (Nn + 15) / 16, Bsz * HEADS);
            qk_k<<<g, dim3(16, 16), 0, stream>>>(Abuf, Sbuf);
        }
        // softmax * SCALE
        softmax_k<<<Bsz * HEADS * Nn, 64, 0, stream>>>(Sbuf);
        // att = P @ V -> Cbuf [6304, 768]
        {
            dim3 g((Nn + 15) / 16, Bsz * HEADS);
            av_k<<<g, 192, 0, stream>>>(Sbuf, Abuf, Cbuf);
        }
        // proj -> Sbuf (first 4.84M floats of it)
        {
            dim3 g((M + 63) / 64, E / 64);
            gemm_k<0><<<g, dim3(16, 16), 0, stream>>>(Cbuf, pw, pb, Sbuf, M, E, E);
        }
        // x = LN(x + proj)
        add_ln_k<<<M, 256, 0, stream>>>(X, Sbuf, g1, b1);
        // hidden = gelu(x @ w1^T + b1) -> Hbuf [6304, 3072]
        {
            dim3 g((M + 63) / 64, FF / 64);
            gemm_k<1><<<g, dim3(16, 16), 0, stream>>>(X, w1, bb1, Hbuf, M, FF, E);
        }
        // mlp = hidden @ w2^T + b2 -> Cbuf
        {
            dim3 g((M + 63) / 64, E / 64);
            gemm_k<0><<<g, dim3(16, 16), 0, stream>>>(Hbuf, w2, bb2, Cbuf, M, E, FF);
        }
        // x = LN(x + mlp)
        add_ln_k<<<M, 256, 0, stream>>>(X, Cbuf, g2, b2);
    }

    // ---- head: mean pool -> LN -> Linear ----
    pool_head_k<<<Bsz, 256, 0, stream>>>(X, hln_g, hln_b, head_w, head_b, out);
}

// Round 2
// 3532.103 us; speedup vs baseline: 3.9257x; 3.9257x over previous
//
#include <hip/hip_runtime.h>
#include <hip/hip_bf16.h>
#include <math.h>

// ---- problem constants ----
constexpr int Bsz = 32, Cch = 3, IMGS = 224, PP = 16;
constexpr int E = 768, HEADS = 8, Lnum = 6, NC = 1000;
constexpr int HD = 96;
constexpr int NP = 196;
constexpr int Nn = 197;
constexpr int FF = 3072;
constexpr float SCALE = 0.10206207261596575f;  // 96^-0.5
constexpr float EPSc  = 1e-5f;

using short8 = __attribute__((ext_vector_type(8))) short;
using f32x4  = __attribute__((ext_vector_type(4))) float;

__device__ __forceinline__ void async_cp16(const void* g, void* l) {
    __builtin_amdgcn_global_load_lds((const __attribute__((address_space(1))) void*)g,
                                     (__attribute__((address_space(3))) void*)l, 16, 0, 0);
}

// =====================================================================
// f32 -> bf16 convert (n must be divisible by 4)
// =====================================================================
__global__ void f2b_k(const float* __restrict__ in, __hip_bfloat16* __restrict__ out, int n4) {
    int i = blockIdx.x * 256 + threadIdx.x;
    if (i >= n4) return;
    const float4 v = ((const float4*)in)[i];
    size_t o = (size_t)i * 4;
    out[o + 0] = __float2bfloat16(v.x);
    out[o + 1] = __float2bfloat16(v.y);
    out[o + 2] = __float2bfloat16(v.z);
    out[o + 3] = __float2bfloat16(v.w);
}

// =====================================================================
// im2col (bf16 out): A[(b*196+p), (c*256+i*16+j)] = x[b,c,ph*16+i,pw*16+j]
// =====================================================================
__global__ void im2col_k(const float* __restrict__ x, __hip_bfloat16* __restrict__ A) {
    int idx = blockIdx.x * 256 + threadIdx.x;
    if (idx >= Bsz * NP * (Cch * PP * PP)) return;
    int col = idx % 768;
    int row = idx / 768;
    int b  = row / NP;
    int p  = row % NP;
    int hh = p / 14, ww = p % 14;
    int c  = col / 256;
    int rem = col % 256;
    int i = rem / 16, j = rem % 16;
    A[idx] = __float2bfloat16(
        x[(((size_t)b * Cch + c) * IMGS + hh * 16 + i) * IMGS + ww * 16 + j]);
}

// =====================================================================
// bf16 MFMA GEMM (m97 structure): out[m,n] = act(bias[n] + sum_k A[m,k]*W[n,k])
// A [M,K] bf16, W [N,K] bf16, K%32==0, N%128==0, M clamped.
// 128x128 tile, BK=32, 4 waves of 4x4 16x16x32 MFMA tiles.
// LDS: [128 rows][4 chunks of 16B], chunk swizzle p = c ^ ((r>>1)&3).
// =====================================================================
template <int OUT_BF16, int ACT>
__global__ __launch_bounds__(256, 2) void gemm_bf16_k(
    const __hip_bfloat16* __restrict__ A, const __hip_bfloat16* __restrict__ W,
    const float* __restrict__ bias, void* __restrict__ outp,
    int M, int N, int K)
{
    __shared__ char As[8192];
    __shared__ char Bs[8192];
    const int tid  = threadIdx.x;
    const int lane = tid & 63;
    const int w    = tid >> 6;
    const int m0 = blockIdx.x * 128, n0 = blockIdx.y * 128;
    const int wm = (w & 1) * 64, wn = (w >> 1) * 64;

    // staging: chunk q = t*256 + w*64 + lane; r=q>>2; phys p=q&3; logical c=p^((r>>1)&3)
    const int q0 = w * 64 + lane, q1 = q0 + 256;
    const int r0 = q0 >> 2, r1 = q1 >> 2;
    const int c0 = (q0 & 3) ^ ((r0 >> 1) & 3);
    const int c1 = (q1 & 3) ^ ((r1 >> 1) & 3);
    int am0 = m0 + r0; if (am0 > M - 1) am0 = M - 1;   // clamp (results masked at store)
    int am1 = m0 + r1; if (am1 > M - 1) am1 = M - 1;
    const __hip_bfloat16* ag0 = A + (size_t)am0 * K + c0 * 8;
    const __hip_bfloat16* ag1 = A + (size_t)am1 * K + c1 * 8;
    const __hip_bfloat16* bg0 = W + (size_t)(n0 + r0) * K + c0 * 8;
    const __hip_bfloat16* bg1 = W + (size_t)(n0 + r1) * K + c1 * 8;
    char* const asd = As + w * 1024;   // wave-uniform LDS dest base (t=0); t=1 at +4096
    char* const bsd = Bs + w * 1024;

    // fragment reads: lane holds A[m = frow][k = fquad*8 + j]
    const int frow = lane & 15, fquad = lane >> 4;
    const int swz = (fquad ^ ((frow >> 1) & 3)) * 16;
    const char* ar = As + (wm + frow) * 64 + swz;
    const char* br = Bs + (wn + frow) * 64 + swz;

    f32x4 acc[4][4] = {};

#pragma unroll 1
    for (int k0 = 0; k0 < K; k0 += 32) {
        async_cp16(ag0 + k0, asd);
        async_cp16(ag1 + k0, asd + 4096);
        async_cp16(bg0 + k0, bsd);
        async_cp16(bg1 + k0, bsd + 4096);
        __syncthreads();
        short8 af[4], bf[4];
#pragma unroll
        for (int i = 0; i < 4; i++) af[i] = *(const short8*)(ar + i * 1024);
#pragma unroll
        for (int j = 0; j < 4; j++) bf[j] = *(const short8*)(br + j * 1024);
#pragma unroll
        for (int i = 0; i < 4; i++)
#pragma unroll
            for (int j = 0; j < 4; j++)
                acc[i][j] = __builtin_amdgcn_mfma_f32_16x16x32_bf16(af[i], bf[j], acc[i][j], 0, 0, 0);
        __syncthreads();
    }

    // epilogue: C/D layout col = lane&15, row = (lane>>4)*4 + reg  [m89-verified]
#pragma unroll
    for (int i = 0; i < 4; i++) {
#pragma unroll
        for (int j = 0; j < 4; j++) {
#pragma unroll
            for (int r = 0; r < 4; r++) {
                int row = m0 + wm + i * 16 + fquad * 4 + r;
                int col = n0 + wn + j * 16 + frow;
                if (row < M) {
                    float v = acc[i][j][r] + bias[col];
                    if (ACT == 1) v = 0.5f * v * (1.0f + erff(v * 0.70710678118654752f));
                    if (OUT_BF16) ((__hip_bfloat16*)outp)[(size_t)row * N + col] = __float2bfloat16(v);
                    else          ((float*)outp)[(size_t)row * N + col] = v;
                }
            }
        }
    }
}

// =====================================================================
// assemble: X/Xb[b,n,e] = (n==0 ? cls[e] : patch[(b,n-1),e]) + pos[n,e]
// =====================================================================
__global__ void assemble_k(const float* __restrict__ ptmp, const float* __restrict__ cls,
                           const float* __restrict__ pos, float* __restrict__ X,
                           __hip_bfloat16* __restrict__ Xb) {
    int idx = blockIdx.x * 256 + threadIdx.x;
    if (idx >= Bsz * Nn * E) return;
    int e = idx % E;
    int r = idx / E;
    int n = r % Nn, b = r / Nn;
    float v = (n == 0) ? cls[e] : ptmp[((size_t)b * NP + (n - 1)) * E + e];
    v += pos[(size_t)n * E + e];
    X[idx] = v;
    Xb[idx] = __float2bfloat16(v);
}

// =====================================================================
// QK^T (bf16 qkv in, f32 sim out)
// =====================================================================
__global__ void qk_k(const __hip_bfloat16* __restrict__ qkv, float* __restrict__ sim) {
    __shared__ float qs[16][97];
    __shared__ float ks[16][97];
    const int bh = blockIdx.z;
    const int b = bh >> 3, h = bh & 7;
    const int i0 = blockIdx.y * 16, j0 = blockIdx.x * 16;
    const int tid = threadIdx.y * 16 + threadIdx.x;
    for (int e = tid; e < 16 * 96; e += 256) {
        int r = e / 96, d = e % 96;
        int gi = i0 + r, gj = j0 + r;
        qs[r][d] = (gi < Nn) ? __bfloat162float(qkv[((size_t)(b * Nn + gi)) * 2304 + h * 96 + d]) : 0.f;
        ks[r][d] = (gj < Nn) ? __bfloat162float(qkv[((size_t)(b * Nn + gj)) * 2304 + 768 + h * 96 + d]) : 0.f;
    }
    __syncthreads();
    const int ii = threadIdx.y, jj = threadIdx.x;
    float acc = 0.f;
#pragma unroll
    for (int d = 0; d < 96; d++) acc += qs[ii][d] * ks[jj][d];
    int gi = i0 + ii, gj = j0 + jj;
    if (gi < Nn && gj < Nn) sim[((size_t)bh * Nn + gi) * Nn + gj] = acc;
}

// =====================================================================
// softmax over 197, then * SCALE (scale AFTER softmax, faithful)
// =====================================================================
__global__ void softmax_k(float* __restrict__ sim) {
    const size_t row = blockIdx.x;
    float* p = sim + row * Nn;
    const int lane = threadIdx.x;
    float vals[4];
    float vmax = -1e30f;
#pragma unroll
    for (int t = 0; t < 4; t++) {
        int j = lane + t * 64;
        vals[t] = (j < Nn) ? p[j] : -1e30f;
        vmax = fmaxf(vmax, vals[t]);
    }
    for (int off = 32; off > 0; off >>= 1) vmax = fmaxf(vmax, __shfl_down(vmax, off));
    vmax = __shfl(vmax, 0);
    float s = 0.f;
#pragma unroll
    for (int t = 0; t < 4; t++) {
        int j = lane + t * 64;
        float ev = (j < Nn) ? expf(vals[t] - vmax) : 0.f;
        vals[t] = ev;
        s += ev;
    }
    for (int off = 32; off > 0; off >>= 1) s += __shfl_down(s, off);
    s = __shfl(s, 0);
    float inv = SCALE / s;
#pragma unroll
    for (int t = 0; t < 4; t++) {
        int j = lane + t * 64;
        if (j < Nn) p[j] = vals[t] * inv;
    }
}

// =====================================================================
// P@V (f32 sim, bf16 v) -> bf16 att
// =====================================================================
__global__ void av_k(const float* __restrict__ sim, const __hip_bfloat16* __restrict__ qkv,
                     __hip_bfloat16* __restrict__ att) {
    __shared__ float ps[16][17];
    __shared__ float vs[16][96];
    const int bh = blockIdx.y;
    const int b = bh >> 3, h = bh & 7;
    const int i0 = blockIdx.x * 16;
    const int t = threadIdx.x;  // 0..191
    const int d = t % 96, iset = t / 96;
    float acc[8] = {};
    for (int j0 = 0; j0 < Nn; j0 += 16) {
        for (int e = t; e < 256; e += 192) {
            int r = e / 16, cj = e % 16;
            int gi = i0 + r, gj = j0 + cj;
            ps[r][cj] = (gi < Nn && gj < Nn) ? sim[((size_t)bh * Nn + gi) * Nn + gj] : 0.f;
        }
        for (int e = t; e < 1536; e += 192) {
            int r = e / 96, dd = e % 96;
            int gj = j0 + r;
            vs[r][dd] = (gj < Nn) ? __bfloat162float(qkv[((size_t)(b * Nn + gj)) * 2304 + 1536 + h * 96 + dd]) : 0.f;
        }
        __syncthreads();
#pragma unroll
        for (int jj = 0; jj < 16; jj++) {
            float vv = vs[jj][d];
#pragma unroll
            for (int r = 0; r < 8; r++) acc[r] += ps[iset * 8 + r][jj] * vv;
        }
        __syncthreads();
    }
#pragma unroll
    for (int r = 0; r < 8; r++) {
        int gi = i0 + iset * 8 + r;
        if (gi < Nn) att[((size_t)(b * Nn + gi)) * E + h * 96 + d] = __float2bfloat16(acc[r]);
    }
}

// =====================================================================
// x = LN(x + t); writes f32 X in place and bf16 shadow Xb
// =====================================================================
__global__ void add_ln_k(float* __restrict__ X, const float* __restrict__ T,
                         const float* __restrict__ g, const float* __restrict__ bb,
                         __hip_bfloat16* __restrict__ Xb) {
    const size_t row = blockIdx.x;
    float* xr = X + row * E;
    const float* tr = T + row * E;
    const int t = threadIdx.x;  // 256
    __shared__ float red[4];
    float v[3];
    float s = 0.f;
#pragma unroll
    for (int i = 0; i < 3; i++) {
        v[i] = xr[t + i * 256] + tr[t + i * 256];
        s += v[i];
    }
    for (int off = 32; off > 0; off >>= 1) s += __shfl_down(s, off);
    int wid = t >> 6, lane = t & 63;
    if (lane == 0) red[wid] = s;
    __syncthreads();
    if (t == 0) red[0] = red[0] + red[1] + red[2] + red[3];
    __syncthreads();
    float mean = red[0] / 768.f;
    __syncthreads();
    float s2 = 0.f;
#pragma unroll
    for (int i = 0; i < 3; i++) {
        float dl = v[i] - mean;
        s2 += dl * dl;
    }
    for (int off = 32; off > 0; off >>= 1) s2 += __shfl_down(s2, off);
    if (lane == 0) red[wid] = s2;
    __syncthreads();
    if (t == 0) red[0] = red[0] + red[1] + red[2] + red[3];
    __syncthreads();
    float rs = rsqrtf(red[0] / 768.f + EPSc);
#pragma unroll
    for (int i = 0; i < 3; i++) {
        int e = t + i * 256;
        float o = (v[i] - mean) * rs * g[e] + bb[e];
        xr[e] = o;
        Xb[row * E + e] = __float2bfloat16(o);
    }
}

// =====================================================================
// mean pool over N + LN -> pooled[b][768] f32
// =====================================================================
__global__ void pool_ln_k(const float* __restrict__ X, const float* __restrict__ g,
                          const float* __restrict__ bb, float* __restrict__ pooled) {
    __shared__ float red[4];
    const int b = blockIdx.x, t = threadIdx.x;
    float loc[3];
#pragma unroll
    for (int i = 0; i < 3; i++) {
        int e = t + i * 256;
        float s = 0.f;
        for (int n = 0; n < Nn; n++) s += X[((size_t)(b * Nn + n)) * E + e];
        loc[i] = s / (float)Nn;
    }
    float s = loc[0] + loc[1] + loc[2];
    for (int off = 32; off > 0; off >>= 1) s += __shfl_down(s, off);
    int wid = t >> 6, lane = t & 63;
    if (lane == 0) red[wid] = s;
    __syncthreads();
    if (t == 0) red[0] = red[0] + red[1] + red[2] + red[3];
    __syncthreads();
    float mean = red[0] / 768.f;
    __syncthreads();
    float s2 = 0.f;
#pragma unroll
    for (int i = 0; i < 3; i++) {
        float dl = loc[i] - mean;
        s2 += dl * dl;
    }
    for (int off = 32; off > 0; off >>= 1) s2 += __shfl_down(s2, off);
    if (lane == 0) red[wid] = s2;
    __syncthreads();
    if (t == 0) red[0] = red[0] + red[1] + red[2] + red[3];
    __syncthreads();
    float rs = rsqrtf(red[0] / 768.f + EPSc);
#pragma unroll
    for (int i = 0; i < 3; i++) {
        int e = t + i * 256;
        pooled[(size_t)b * E + e] = (loc[i] - mean) * rs * g[e] + bb[e];
    }
}

// =====================================================================
// head matvec: out[b,o] = hb[o] + pooled[b,:] . hw[o,:]
// grid (25, 32); block 256 = 4 waves; wave handles 10 outputs, coalesced
// =====================================================================
__global__ void head_k(const float* __restrict__ pooled, const float* __restrict__ hw,
                       const float* __restrict__ hb, float* __restrict__ out) {
    __shared__ float ps[768];
    const int b = blockIdx.y;
    const int s = blockIdx.x;
    const int t = threadIdx.x, lane = t & 63, w = t >> 6;
    for (int e = t; e < 768; e += 256) ps[e] = pooled[(size_t)b * E + e];
    __syncthreads();
    float pl[12];
#pragma unroll
    for (int j = 0; j < 12; j++) pl[j] = ps[j * 64 + lane];
    for (int i = 0; i < 10; i++) {
        int o = s * 40 + w * 10 + i;
        const float* wr = hw + (size_t)o * 768;
        float acc = 0.f;
#pragma unroll
        for (int j = 0; j < 12; j++) acc += pl[j] * wr[j * 64 + lane];
        for (int off = 32; off > 0; off >>= 1) acc += __shfl_down(acc, off);
        if (lane == 0) out[(size_t)b * NC + o] = acc + hb[o];
    }
}

// =====================================================================
extern "C" void kernel_launch(void* const* d_in, const int* in_sizes, int n_in,
                              void* d_out, int out_size, void* d_ws, size_t ws_size,
                              hipStream_t stream) {
    const float* x        = (const float*)d_in[0];
    const float* conv_w   = (const float*)d_in[1];
    const float* conv_b   = (const float*)d_in[2];
    const float* cls_tok  = (const float*)d_in[3];
    const float* pos_emb  = (const float*)d_in[4];
    const float* qkv_w    = (const float*)d_in[5];
    const float* qkv_b    = (const float*)d_in[6];
    const float* proj_w   = (const float*)d_in[7];
    const float* proj_b   = (const float*)d_in[8];
    const float* ln1_g    = (const float*)d_in[9];
    const float* ln1_b    = (const float*)d_in[10];
    const float* mlp_w1   = (const float*)d_in[11];
    const float* mlp_b1   = (const float*)d_in[12];
    const float* mlp_w2   = (const float*)d_in[13];
    const float* mlp_b2   = (const float*)d_in[14];
    const float* ln2_g    = (const float*)d_in[15];
    const float* ln2_b    = (const float*)d_in[16];
    const float* hln_g    = (const float*)d_in[17];
    const float* hln_b    = (const float*)d_in[18];
    const float* head_w   = (const float*)d_in[19];
    const float* head_b   = (const float*)d_in[20];
    float* out = (float*)d_out;

    const int M = Bsz * Nn;  // 6304

    // ---- workspace carve-up (bytes), all 256-aligned; total ~117 MB ----
    char* p = (char*)d_ws;
    __hip_bfloat16* Xb   = (__hip_bfloat16*)p;            p += (size_t)M * E * 2;          // 9,682,944
    float*          X    = (float*)p;                     p += (size_t)M * E * 4;          // 19,365,888
    __hip_bfloat16* qwb  = (__hip_bfloat16*)p;            p += (size_t)3 * E * E * 2;      // 3,538,944
    __hip_bfloat16* pwb  = (__hip_bfloat16*)p;            p += (size_t)E * E * 2;          // 1,179,648
    __hip_bfloat16* w1b  = (__hip_bfloat16*)p;            p += (size_t)FF * E * 2;         // 4,718,592
    __hip_bfloat16* w2b  = (__hip_bfloat16*)p;            p += (size_t)E * FF * 2;         // 4,718,592
    __hip_bfloat16* cwb  = (__hip_bfloat16*)p;            p += (size_t)E * E * 2;          // 1,179,648
    __hip_bfloat16* attb = (__hip_bfloat16*)p;            p += (size_t)M * E * 2;          // 9,682,944
    float*          pool = (float*)p;                     p += (size_t)Bsz * E * 4;        // 98,304
    char* R = p;  // shared region, 68,789,248 bytes
    __hip_bfloat16* qkvb = (__hip_bfloat16*)R;                           // 29,048,832
    float*          sim  = (float*)(R + 29048832);                       // 39,740,416
    __hip_bfloat16* Hb   = (__hip_bfloat16*)R;                           // 38,731,776
    float*          Ctmp = (float*)(R + 38731776);                       // 19,365,888
    __hip_bfloat16* imb  = (__hip_bfloat16*)R;                           // 9,633,792

    // ---- patch embed ----
    {
        f2b_k<<<(E * E / 4 + 255) / 256, 256, 0, stream>>>(conv_w, cwb, E * E / 4);
        int tot = Bsz * NP * 768;
        im2col_k<<<(tot + 255) / 256, 256, 0, stream>>>(x, imb);
        dim3 g(49, 6);  // M=6272 exactly 49*128, N=768
        gemm_bf16_k<0, 0><<<g, 256, 0, stream>>>(imb, cwb, conv_b, Ctmp, Bsz * NP, E, E);
        int tot2 = Bsz * Nn * E;
        assemble_k<<<(tot2 + 255) / 256, 256, 0, stream>>>(Ctmp, cls_tok, pos_emb, X, Xb);
    }

    const int MB = (M + 127) / 128;  // 50

    // ---- transformer layers ----
    for (int l = 0; l < Lnum; l++) {
        const float* qw = qkv_w + (size_t)l * 3 * E * E;
        const float* qb = qkv_b + (size_t)l * 3 * E;
        const float* pw = proj_w + (size_t)l * E * E;
        const float* pb = proj_b + (size_t)l * E;
        const float* g1 = ln1_g + (size_t)l * E;
        const float* b1 = ln1_b + (size_t)l * E;
        const float* w1 = mlp_w1 + (size_t)l * FF * E;
        const float* bb1 = mlp_b1 + (size_t)l * FF;
        const float* w2 = mlp_w2 + (size_t)l * E * FF;
        const float* bb2 = mlp_b2 + (size_t)l * E;
        const float* g2 = ln2_g + (size_t)l * E;
        const float* b2 = ln2_b + (size_t)l * E;

        // convert this layer's weights to bf16
        f2b_k<<<(3 * E * E / 4 + 255) / 256, 256, 0, stream>>>(qw, qwb, 3 * E * E / 4);
        f2b_k<<<(E * E / 4 + 255) / 256, 256, 0, stream>>>(pw, pwb, E * E / 4);
        f2b_k<<<(FF * E / 4 + 255) / 256, 256, 0, stream>>>(w1, w1b, FF * E / 4);
        f2b_k<<<(E * FF / 4 + 255) / 256, 256, 0, stream>>>(w2, w2b, E * FF / 4);

        // qkv = Xb @ qwb^T -> bf16 [M, 2304]
        gemm_bf16_k<1, 0><<<dim3(MB, 18), 256, 0, stream>>>(Xb, qwb, qb, qkvb, M, 3 * E, E);
        // sim = q @ k^T -> f32
        qk_k<<<dim3(13, 13, Bsz * HEADS), dim3(16, 16), 0, stream>>>(qkvb, sim);
        softmax_k<<<Bsz * HEADS * Nn, 64, 0, stream>>>(sim);
        // att = P @ V -> bf16 [M, 768]
        av_k<<<dim3(13, Bsz * HEADS), 192, 0, stream>>>(sim, qkvb, attb);
        // proj -> f32 Ctmp
        gemm_bf16_k<0, 0><<<dim3(MB, 6), 256, 0, stream>>>(attb, pwb, pb, Ctmp, M, E, E);
        add_ln_k<<<M, 256, 0, stream>>>(X, Ctmp, g1, b1, Xb);
        // MLP1 + gelu -> bf16 Hb [M, 3072]
        gemm_bf16_k<1, 1><<<dim3(MB, 24), 256, 0, stream>>>(Xb, w1b, bb1, Hb, M, FF, E);
        // MLP2 -> f32 Ctmp
        gemm_bf16_k<0, 0><<<dim3(MB, 6), 256, 0, stream>>>(Hb, w2b, bb2, Ctmp, M, E, FF);
        add_ln_k<<<M, 256, 0, stream>>>(X, Ctmp, g2, b2, Xb);
    }

    // ---- head ----
    pool_ln_k<<<Bsz, 256, 0, stream>>>(X, hln_g, hln_b, pool);
    head_k<<<dim3(25, Bsz), 256, 0, stream>>>(pool, head_w, head_b, out);
}

// Round 3
// 2315.664 us; speedup vs baseline: 5.9879x; 1.5253x over previous
//
#include <hip/hip_runtime.h>
#include <hip/hip_bf16.h>
#include <math.h>

// ---- problem constants ----
constexpr int Bsz = 32, Cch = 3, IMGS = 224, PP = 16;
constexpr int E = 768, HEADS = 8, Lnum = 6, NC = 1000;
constexpr int HD = 96;
constexpr int NP = 196;
constexpr int Nn = 197;
constexpr int FF = 3072;
constexpr float SCALE = 0.10206207261596575f;  // 96^-0.5
constexpr float EPSc  = 1e-5f;

using short8 = __attribute__((ext_vector_type(8))) short;
using f32x4  = __attribute__((ext_vector_type(4))) float;

__device__ __forceinline__ void async_cp16(const void* g, void* l) {
    __builtin_amdgcn_global_load_lds((const __attribute__((address_space(1))) void*)g,
                                     (__attribute__((address_space(3))) void*)l, 16, 0, 0);
}

// =====================================================================
// f32 -> bf16 convert
// =====================================================================
__global__ void f2b_k(const float* __restrict__ in, __hip_bfloat16* __restrict__ out, int n4) {
    int i = blockIdx.x * 256 + threadIdx.x;
    if (i >= n4) return;
    const float4 v = ((const float4*)in)[i];
    size_t o = (size_t)i * 4;
    out[o + 0] = __float2bfloat16(v.x);
    out[o + 1] = __float2bfloat16(v.y);
    out[o + 2] = __float2bfloat16(v.z);
    out[o + 3] = __float2bfloat16(v.w);
}

// =====================================================================
// im2col (bf16 out)
// =====================================================================
__global__ void im2col_k(const float* __restrict__ x, __hip_bfloat16* __restrict__ A) {
    int idx = blockIdx.x * 256 + threadIdx.x;
    if (idx >= Bsz * NP * (Cch * PP * PP)) return;
    int col = idx % 768;
    int row = idx / 768;
    int b  = row / NP;
    int p  = row % NP;
    int hh = p / 14, ww = p % 14;
    int c  = col / 256;
    int rem = col % 256;
    int i = rem / 16, j = rem % 16;
    A[idx] = __float2bfloat16(
        x[(((size_t)b * Cch + c) * IMGS + hh * 16 + i) * IMGS + ww * 16 + j]);
}

// =====================================================================
// bf16 MFMA GEMM (m97 structure), unchanged from round 2
// =====================================================================
template <int OUT_BF16, int ACT>
__global__ __launch_bounds__(256, 2) void gemm_bf16_k(
    const __hip_bfloat16* __restrict__ A, const __hip_bfloat16* __restrict__ W,
    const float* __restrict__ bias, void* __restrict__ outp,
    int M, int N, int K)
{
    __shared__ char As[8192];
    __shared__ char Bs[8192];
    const int tid  = threadIdx.x;
    const int lane = tid & 63;
    const int w    = tid >> 6;
    const int m0 = blockIdx.x * 128, n0 = blockIdx.y * 128;
    const int wm = (w & 1) * 64, wn = (w >> 1) * 64;

    const int q0 = w * 64 + lane, q1 = q0 + 256;
    const int r0 = q0 >> 2, r1 = q1 >> 2;
    const int c0 = (q0 & 3) ^ ((r0 >> 1) & 3);
    const int c1 = (q1 & 3) ^ ((r1 >> 1) & 3);
    int am0 = m0 + r0; if (am0 > M - 1) am0 = M - 1;
    int am1 = m0 + r1; if (am1 > M - 1) am1 = M - 1;
    const __hip_bfloat16* ag0 = A + (size_t)am0 * K + c0 * 8;
    const __hip_bfloat16* ag1 = A + (size_t)am1 * K + c1 * 8;
    const __hip_bfloat16* bg0 = W + (size_t)(n0 + r0) * K + c0 * 8;
    const __hip_bfloat16* bg1 = W + (size_t)(n0 + r1) * K + c1 * 8;
    char* const asd = As + w * 1024;
    char* const bsd = Bs + w * 1024;

    const int frow = lane & 15, fquad = lane >> 4;
    const int swz = (fquad ^ ((frow >> 1) & 3)) * 16;
    const char* ar = As + (wm + frow) * 64 + swz;
    const char* br = Bs + (wn + frow) * 64 + swz;

    f32x4 acc[4][4] = {};

#pragma unroll 1
    for (int k0 = 0; k0 < K; k0 += 32) {
        async_cp16(ag0 + k0, asd);
        async_cp16(ag1 + k0, asd + 4096);
        async_cp16(bg0 + k0, bsd);
        async_cp16(bg1 + k0, bsd + 4096);
        __syncthreads();
        short8 af[4], bf[4];
#pragma unroll
        for (int i = 0; i < 4; i++) af[i] = *(const short8*)(ar + i * 1024);
#pragma unroll
        for (int j = 0; j < 4; j++) bf[j] = *(const short8*)(br + j * 1024);
#pragma unroll
        for (int i = 0; i < 4; i++)
#pragma unroll
            for (int j = 0; j < 4; j++)
                acc[i][j] = __builtin_amdgcn_mfma_f32_16x16x32_bf16(af[i], bf[j], acc[i][j], 0, 0, 0);
        __syncthreads();
    }

#pragma unroll
    for (int i = 0; i < 4; i++) {
#pragma unroll
        for (int j = 0; j < 4; j++) {
#pragma unroll
            for (int r = 0; r < 4; r++) {
                int row = m0 + wm + i * 16 + fquad * 4 + r;
                int col = n0 + wn + j * 16 + frow;
                if (row < M) {
                    float v = acc[i][j][r] + bias[col];
                    if (ACT == 1) v = 0.5f * v * (1.0f + erff(v * 0.70710678118654752f));
                    if (OUT_BF16) ((__hip_bfloat16*)outp)[(size_t)row * N + col] = __float2bfloat16(v);
                    else          ((float*)outp)[(size_t)row * N + col] = v;
                }
            }
        }
    }
}

// =====================================================================
// assemble
// =====================================================================
__global__ void assemble_k(const float* __restrict__ ptmp, const float* __restrict__ cls,
                           const float* __restrict__ pos, float* __restrict__ X,
                           __hip_bfloat16* __restrict__ Xb) {
    int idx = blockIdx.x * 256 + threadIdx.x;
    if (idx >= Bsz * Nn * E) return;
    int e = idx % E;
    int r = idx / E;
    int n = r % Nn, b = r / Nn;
    float v = (n == 0) ? cls[e] : ptmp[((size_t)b * NP + (n - 1)) * E + e];
    v += pos[(size_t)n * E + e];
    X[idx] = v;
    Xb[idx] = __float2bfloat16(v);
}

// =====================================================================
// V transpose: Vtg[bh][d][j] (row stride 232 shorts), j padded cols zeroed
// grid (4, 256), block 256. LDS tile 64j x 96d.
// =====================================================================
__global__ void vtr_k(const __hip_bfloat16* __restrict__ qkv, __hip_bfloat16* __restrict__ Vtg) {
    __shared__ short T[64][104];   // 208B row stride (52 dw)
    const int tid = threadIdx.x;
    const int bh = blockIdx.y, jc = blockIdx.x;
    const int b = bh >> 3, h = bh & 7;
    const int j0 = jc * 64;
#pragma unroll
    for (int it = 0; it < 3; it++) {
        int idx = it * 256 + tid;
        int jl = idx / 12, off = (idx % 12) * 8;
        int j = j0 + jl;
        short8 v = {0, 0, 0, 0, 0, 0, 0, 0};
        if (j <= 196)
            v = *(const short8*)(qkv + (size_t)(b * Nn + j) * 2304 + 1536 + h * 96 + off);
        *(short8*)(&T[jl][off]) = v;
    }
    __syncthreads();
#pragma unroll
    for (int it = 0; it < 3; it++) {
        int idx = it * 256 + tid;
        int d = idx >> 3, c = idx & 7;
        int col = j0 + c * 8;
        if (col < 232) {
            short8 v;
#pragma unroll
            for (int k = 0; k < 8; k++) v[k] = T[c * 8 + k][d];
            *(short8*)(Vtg + ((size_t)bh * 96 + d) * 232 + col) = v;
        }
    }
}

// =====================================================================
// Fused attention: per (b,h) x 4-way m-split. Block 256 = 4 waves,
// wave handles m-tile mt = s + 4*w (16 query rows).
// S = Q K^T via MFMA (Q,K frags from global), softmax in C-layout regs,
// P -> A-layout via per-wave LDS scratch, O = P V via MFMA vs LDS Vt.
// =====================================================================
__global__ __launch_bounds__(256, 2) void fattn_k(
    const __hip_bfloat16* __restrict__ qkv,
    const __hip_bfloat16* __restrict__ Vtg,
    __hip_bfloat16* __restrict__ att)
{
    __shared__ __align__(16) char Vt[96 * 464];   // 44544 B, row stride 464B (116 dw)
    __shared__ __align__(16) char Ps[4 * 1280];   // per-wave 16 x 80B
    const int tid = threadIdx.x, lane = tid & 63, w = tid >> 6;
    const int bh = blockIdx.x >> 2, s = blockIdx.x & 3;
    const int b = bh >> 3, h = bh & 7;
    const int frow = lane & 15, quad = lane >> 4;

    // DMA whole V^T head slab (contiguous 96*464B) into LDS
    const char* src = (const char*)(Vtg + (size_t)bh * 96 * 232);
    for (int i = 0; i < 11; i++) {
        int c = i * 256 + w * 64 + lane;
        if (c < 96 * 29)
            async_cp16(src + (size_t)c * 16, Vt + (size_t)(i * 256 + w * 64) * 16);
    }
    __syncthreads();

    const int mt = s + 4 * w;
    if (mt < 13) {
        // Q fragments (A-layout): lane -> row mt*16+frow, k = quad*8.. per 32-chunk
        const int qi = min(mt * 16 + frow, 196);
        const __hip_bfloat16* qrow = qkv + (size_t)(b * Nn + qi) * 2304 + h * 96 + quad * 8;
        short8 qf[3];
#pragma unroll
        for (int kc = 0; kc < 3; kc++) qf[kc] = *(const short8*)(qrow + kc * 32);

        // S strip: 13 n-tiles, C-layout acc
        f32x4 sacc[13];
#pragma unroll
        for (int nt = 0; nt < 13; nt++) sacc[nt] = (f32x4){0.f, 0.f, 0.f, 0.f};
#pragma unroll 1
        for (int nt = 0; nt < 13; nt++) {
            const int kj = min(nt * 16 + frow, 196);
            const __hip_bfloat16* krow = qkv + (size_t)(b * Nn + kj) * 2304 + 768 + h * 96 + quad * 8;
#pragma unroll
            for (int kc = 0; kc < 3; kc++) {
                short8 kf = *(const short8*)(krow + kc * 32);
                sacc[nt] = __builtin_amdgcn_mfma_f32_16x16x32_bf16(qf[kc], kf, sacc[nt], 0, 0, 0);
            }
        }

        // softmax over cols (row = quad*4+r spread over 16-lane group, col = nt*16+frow)
        float mx[4] = {-1e30f, -1e30f, -1e30f, -1e30f};
#pragma unroll
        for (int nt = 0; nt < 13; nt++) {
            bool masked = (nt == 12) && (frow >= 5);  // col > 196
#pragma unroll
            for (int r = 0; r < 4; r++) {
                float v = masked ? -1e30f : sacc[nt][r];
                sacc[nt][r] = v;
                mx[r] = fmaxf(mx[r], v);
            }
        }
#pragma unroll
        for (int m = 1; m <= 8; m <<= 1)
#pragma unroll
            for (int r = 0; r < 4; r++) mx[r] = fmaxf(mx[r], __shfl_xor(mx[r], m));
        float sm[4] = {0.f, 0.f, 0.f, 0.f};
#pragma unroll
        for (int nt = 0; nt < 13; nt++) {
            bool masked = (nt == 12) && (frow >= 5);
#pragma unroll
            for (int r = 0; r < 4; r++) {
                float e = masked ? 0.f : __expf(sacc[nt][r] - mx[r]);
                sacc[nt][r] = e;
                sm[r] += e;
            }
        }
#pragma unroll
        for (int m = 1; m <= 8; m <<= 1)
#pragma unroll
            for (int r = 0; r < 4; r++) sm[r] += __shfl_xor(sm[r], m);
        float inv[4];
#pragma unroll
        for (int r = 0; r < 4; r++) inv[r] = SCALE / sm[r];

        // O = P V
        f32x4 oacc[6];
#pragma unroll
        for (int dt = 0; dt < 6; dt++) oacc[dt] = (f32x4){0.f, 0.f, 0.f, 0.f};
        char* const myPs = Ps + w * 1280;
#pragma unroll 1
        for (int kc = 0; kc < 7; kc++) {
#pragma unroll
            for (int tt = 0; tt < 2; tt++) {
                int t = kc * 2 + tt;
#pragma unroll
                for (int r = 0; r < 4; r++) {
                    float pv = (t < 13) ? sacc[t][r] * inv[r] : 0.f;
                    *(__hip_bfloat16*)(myPs + (quad * 4 + r) * 80 + (tt * 16 + frow) * 2) =
                        __float2bfloat16(pv);
                }
            }
            short8 pf = *(const short8*)(myPs + frow * 80 + quad * 16);
#pragma unroll
            for (int dt = 0; dt < 6; dt++) {
                short8 vf = *(const short8*)(Vt + (size_t)(dt * 16 + frow) * 464 +
                                             (kc * 32 + quad * 8) * 2);
                oacc[dt] = __builtin_amdgcn_mfma_f32_16x16x32_bf16(pf, vf, oacc[dt], 0, 0, 0);
            }
        }

        // store O (C-layout): row i = mt*16 + quad*4 + r, col d = dt*16 + frow
#pragma unroll
        for (int dt = 0; dt < 6; dt++)
#pragma unroll
            for (int r = 0; r < 4; r++) {
                int i = mt * 16 + quad * 4 + r;
                if (i < Nn)
                    att[(size_t)(b * Nn + i) * 768 + h * 96 + dt * 16 + frow] =
                        __float2bfloat16(oacc[dt][r]);
            }
    }
}

// =====================================================================
// x = LN(x + t); writes f32 X in place and bf16 shadow Xb
// =====================================================================
__global__ void add_ln_k(float* __restrict__ X, const float* __restrict__ T,
                         const float* __restrict__ g, const float* __restrict__ bb,
                         __hip_bfloat16* __restrict__ Xb) {
    const size_t row = blockIdx.x;
    float* xr = X + row * E;
    const float* tr = T + row * E;
    const int t = threadIdx.x;
    __shared__ float red[4];
    float v[3];
    float s = 0.f;
#pragma unroll
    for (int i = 0; i < 3; i++) {
        v[i] = xr[t + i * 256] + tr[t + i * 256];
        s += v[i];
    }
    for (int off = 32; off > 0; off >>= 1) s += __shfl_down(s, off);
    int wid = t >> 6, lane = t & 63;
    if (lane == 0) red[wid] = s;
    __syncthreads();
    if (t == 0) red[0] = red[0] + red[1] + red[2] + red[3];
    __syncthreads();
    float mean = red[0] / 768.f;
    __syncthreads();
    float s2 = 0.f;
#pragma unroll
    for (int i = 0; i < 3; i++) {
        float dl = v[i] - mean;
        s2 += dl * dl;
    }
    for (int off = 32; off > 0; off >>= 1) s2 += __shfl_down(s2, off);
    if (lane == 0) red[wid] = s2;
    __syncthreads();
    if (t == 0) red[0] = red[0] + red[1] + red[2] + red[3];
    __syncthreads();
    float rs = rsqrtf(red[0] / 768.f + EPSc);
#pragma unroll
    for (int i = 0; i < 3; i++) {
        int e = t + i * 256;
        float o = (v[i] - mean) * rs * g[e] + bb[e];
        xr[e] = o;
        Xb[row * E + e] = __float2bfloat16(o);
    }
}

// =====================================================================
// mean pool over N + LN -> pooled
// =====================================================================
__global__ void pool_ln_k(const float* __restrict__ X, const float* __restrict__ g,
                          const float* __restrict__ bb, float* __restrict__ pooled) {
    __shared__ float red[4];
    const int b = blockIdx.x, t = threadIdx.x;
    float loc[3];
#pragma unroll
    for (int i = 0; i < 3; i++) {
        int e = t + i * 256;
        float s = 0.f;
        for (int n = 0; n < Nn; n++) s += X[((size_t)(b * Nn + n)) * E + e];
        loc[i] = s / (float)Nn;
    }
    float s = loc[0] + loc[1] + loc[2];
    for (int off = 32; off > 0; off >>= 1) s += __shfl_down(s, off);
    int wid = t >> 6, lane = t & 63;
    if (lane == 0) red[wid] = s;
    __syncthreads();
    if (t == 0) red[0] = red[0] + red[1] + red[2] + red[3];
    __syncthreads();
    float mean = red[0] / 768.f;
    __syncthreads();
    float s2 = 0.f;
#pragma unroll
    for (int i = 0; i < 3; i++) {
        float dl = loc[i] - mean;
        s2 += dl * dl;
    }
    for (int off = 32; off > 0; off >>= 1) s2 += __shfl_down(s2, off);
    if (lane == 0) red[wid] = s2;
    __syncthreads();
    if (t == 0) red[0] = red[0] + red[1] + red[2] + red[3];
    __syncthreads();
    float rs = rsqrtf(red[0] / 768.f + EPSc);
#pragma unroll
    for (int i = 0; i < 3; i++) {
        int e = t + i * 256;
        pooled[(size_t)b * E + e] = (loc[i] - mean) * rs * g[e] + bb[e];
    }
}

// =====================================================================
// head matvec
// =====================================================================
__global__ void head_k(const float* __restrict__ pooled, const float* __restrict__ hw,
                       const float* __restrict__ hb, float* __restrict__ out) {
    __shared__ float ps[768];
    const int b = blockIdx.y;
    const int s = blockIdx.x;
    const int t = threadIdx.x, lane = t & 63, w = t >> 6;
    for (int e = t; e < 768; e += 256) ps[e] = pooled[(size_t)b * E + e];
    __syncthreads();
    float pl[12];
#pragma unroll
    for (int j = 0; j < 12; j++) pl[j] = ps[j * 64 + lane];
    for (int i = 0; i < 10; i++) {
        int o = s * 40 + w * 10 + i;
        const float* wr = hw + (size_t)o * 768;
        float acc = 0.f;
#pragma unroll
        for (int j = 0; j < 12; j++) acc += pl[j] * wr[j * 64 + lane];
        for (int off = 32; off > 0; off >>= 1) acc += __shfl_down(acc, off);
        if (lane == 0) out[(size_t)b * NC + o] = acc + hb[o];
    }
}

// =====================================================================
extern "C" void kernel_launch(void* const* d_in, const int* in_sizes, int n_in,
                              void* d_out, int out_size, void* d_ws, size_t ws_size,
                              hipStream_t stream) {
    const float* x        = (const float*)d_in[0];
    const float* conv_w   = (const float*)d_in[1];
    const float* conv_b   = (const float*)d_in[2];
    const float* cls_tok  = (const float*)d_in[3];
    const float* pos_emb  = (const float*)d_in[4];
    const float* qkv_w    = (const float*)d_in[5];
    const float* qkv_b    = (const float*)d_in[6];
    const float* proj_w   = (const float*)d_in[7];
    const float* proj_b   = (const float*)d_in[8];
    const float* ln1_g    = (const float*)d_in[9];
    const float* ln1_b    = (const float*)d_in[10];
    const float* mlp_w1   = (const float*)d_in[11];
    const float* mlp_b1   = (const float*)d_in[12];
    const float* mlp_w2   = (const float*)d_in[13];
    const float* mlp_b2   = (const float*)d_in[14];
    const float* ln2_g    = (const float*)d_in[15];
    const float* ln2_b    = (const float*)d_in[16];
    const float* hln_g    = (const float*)d_in[17];
    const float* hln_b    = (const float*)d_in[18];
    const float* head_w   = (const float*)d_in[19];
    const float* head_b   = (const float*)d_in[20];
    float* out = (float*)d_out;

    const int M = Bsz * Nn;  // 6304

    // ---- workspace carve-up ----
    char* p = (char*)d_ws;
    __hip_bfloat16* Xb   = (__hip_bfloat16*)p;  p += (size_t)M * E * 2;
    float*          X    = (float*)p;           p += (size_t)M * E * 4;
    __hip_bfloat16* qwb  = (__hip_bfloat16*)p;  p += (size_t)3 * E * E * 2;
    __hip_bfloat16* pwb  = (__hip_bfloat16*)p;  p += (size_t)E * E * 2;
    __hip_bfloat16* w1b  = (__hip_bfloat16*)p;  p += (size_t)FF * E * 2;
    __hip_bfloat16* w2b  = (__hip_bfloat16*)p;  p += (size_t)E * FF * 2;
    __hip_bfloat16* cwb  = (__hip_bfloat16*)p;  p += (size_t)E * E * 2;
    __hip_bfloat16* attb = (__hip_bfloat16*)p;  p += (size_t)M * E * 2;
    float*          pool = (float*)p;           p += (size_t)Bsz * E * 4;
    char* R = p;
    // live set A (attention): qkvb [29,048,832 B] + Vtg [11,403,264 B]
    // live set B (patch/MLP): Hb [38,731,776 B] + Ctmp [19,365,888 B]
    __hip_bfloat16* qkvb = (__hip_bfloat16*)R;
    __hip_bfloat16* Vtg  = (__hip_bfloat16*)(R + 29048832);
    __hip_bfloat16* Hb   = (__hip_bfloat16*)R;
    float*          Ctmp = (float*)(R + 40452096);
    __hip_bfloat16* imb  = (__hip_bfloat16*)R;

    // ---- patch embed ----
    {
        f2b_k<<<(E * E / 4 + 255) / 256, 256, 0, stream>>>(conv_w, cwb, E * E / 4);
        int tot = Bsz * NP * 768;
        im2col_k<<<(tot + 255) / 256, 256, 0, stream>>>(x, imb);
        dim3 g(49, 6);
        gemm_bf16_k<0, 0><<<g, 256, 0, stream>>>(imb, cwb, conv_b, Ctmp, Bsz * NP, E, E);
        int tot2 = Bsz * Nn * E;
        assemble_k<<<(tot2 + 255) / 256, 256, 0, stream>>>(Ctmp, cls_tok, pos_emb, X, Xb);
    }

    const int MB = (M + 127) / 128;  // 50

    // ---- transformer layers ----
    for (int l = 0; l < Lnum; l++) {
        const float* qw = qkv_w + (size_t)l * 3 * E * E;
        const float* qb = qkv_b + (size_t)l * 3 * E;
        const float* pw = proj_w + (size_t)l * E * E;
        const float* pb = proj_b + (size_t)l * E;
        const float* g1 = ln1_g + (size_t)l * E;
        const float* b1 = ln1_b + (size_t)l * E;
        const float* w1 = mlp_w1 + (size_t)l * FF * E;
        const float* bb1 = mlp_b1 + (size_t)l * FF;
        const float* w2 = mlp_w2 + (size_t)l * E * FF;
        const float* bb2 = mlp_b2 + (size_t)l * E;
        const float* g2 = ln2_g + (size_t)l * E;
        const float* b2 = ln2_b + (size_t)l * E;

        f2b_k<<<(3 * E * E / 4 + 255) / 256, 256, 0, stream>>>(qw, qwb, 3 * E * E / 4);
        f2b_k<<<(E * E / 4 + 255) / 256, 256, 0, stream>>>(pw, pwb, E * E / 4);
        f2b_k<<<(FF * E / 4 + 255) / 256, 256, 0, stream>>>(w1, w1b, FF * E / 4);
        f2b_k<<<(E * FF / 4 + 255) / 256, 256, 0, stream>>>(w2, w2b, E * FF / 4);

        // qkv = Xb @ qwb^T -> bf16 [M, 2304]
        gemm_bf16_k<1, 0><<<dim3(MB, 18), 256, 0, stream>>>(Xb, qwb, qb, qkvb, M, 3 * E, E);
        // V transpose into Vtg
        vtr_k<<<dim3(4, Bsz * HEADS), 256, 0, stream>>>(qkvb, Vtg);
        // fused attention -> attb
        fattn_k<<<Bsz * HEADS * 4, 256, 0, stream>>>(qkvb, Vtg, attb);
        // proj -> f32 Ctmp
        gemm_bf16_k<0, 0><<<dim3(MB, 6), 256, 0, stream>>>(attb, pwb, pb, Ctmp, M, E, E);
        add_ln_k<<<M, 256, 0, stream>>>(X, Ctmp, g1, b1, Xb);
        // MLP1 + gelu -> bf16 Hb
        gemm_bf16_k<1, 1><<<dim3(MB, 24), 256, 0, stream>>>(Xb, w1b, bb1, Hb, M, FF, E);
        // MLP2 -> f32 Ctmp
        gemm_bf16_k<0, 0><<<dim3(MB, 6), 256, 0, stream>>>(Hb, w2b, bb2, Ctmp, M, E, FF);
        add_ln_k<<<M, 256, 0, stream>>>(X, Ctmp, g2, b2, Xb);
    }

    // ---- head ----
    pool_ln_k<<<Bsz, 256, 0, stream>>>(X, hln_g, hln_b, pool);
    head_k<<<dim3(25, Bsz), 256, 0, stream>>>(pool, head_w, head_b, out);
}

// Round 4
// 2037.313 us; speedup vs baseline: 6.8060x; 1.1366x over previous
//
#include <hip/hip_runtime.h>
#include <hip/hip_bf16.h>
#include <math.h>

// ---- problem constants ----
constexpr int Bsz = 32, Cch = 3, IMGS = 224, PP = 16;
constexpr int E = 768, HEADS = 8, Lnum = 6, NC = 1000;
constexpr int HD = 96;
constexpr int NP = 196;
constexpr int Nn = 197;
constexpr int FF = 3072;
constexpr float SCALE = 0.10206207261596575f;  // 96^-0.5
constexpr float EPSc  = 1e-5f;

using short8 = __attribute__((ext_vector_type(8))) short;
using f32x4  = __attribute__((ext_vector_type(4))) float;

__device__ __forceinline__ void async_cp16(const void* g, void* l) {
    __builtin_amdgcn_global_load_lds((const __attribute__((address_space(1))) void*)g,
                                     (__attribute__((address_space(3))) void*)l, 16, 0, 0);
}

// =====================================================================
// f32 -> bf16 convert (single tensor)
// =====================================================================
__global__ void f2b_k(const float* __restrict__ in, __hip_bfloat16* __restrict__ out, int n4) {
    int i = blockIdx.x * 256 + threadIdx.x;
    if (i >= n4) return;
    const float4 v = ((const float4*)in)[i];
    size_t o = (size_t)i * 4;
    out[o + 0] = __float2bfloat16(v.x);
    out[o + 1] = __float2bfloat16(v.y);
    out[o + 2] = __float2bfloat16(v.z);
    out[o + 3] = __float2bfloat16(v.w);
}

// =====================================================================
// fused 4-tensor f32 -> bf16 (one dispatch per layer's weights)
// n* in float4 units
// =====================================================================
__global__ void f2b4_k(const float* __restrict__ s0, const float* __restrict__ s1,
                       const float* __restrict__ s2, const float* __restrict__ s3,
                       __hip_bfloat16* __restrict__ d0, __hip_bfloat16* __restrict__ d1,
                       __hip_bfloat16* __restrict__ d2, __hip_bfloat16* __restrict__ d3,
                       int n0, int n1, int n2, int n3) {
    int i = blockIdx.x * 256 + threadIdx.x;
    const float* s; __hip_bfloat16* d; int base;
    if (i < n0)                { s = s0; d = d0; base = 0; }
    else if (i < n0 + n1)      { s = s1; d = d1; base = n0; }
    else if (i < n0 + n1 + n2) { s = s2; d = d2; base = n0 + n1; }
    else if (i < n0 + n1 + n2 + n3) { s = s3; d = d3; base = n0 + n1 + n2; }
    else return;
    int k = i - base;
    const float4 v = ((const float4*)s)[k];
    size_t o = (size_t)k * 4;
    d[o + 0] = __float2bfloat16(v.x);
    d[o + 1] = __float2bfloat16(v.y);
    d[o + 2] = __float2bfloat16(v.z);
    d[o + 3] = __float2bfloat16(v.w);
}

// =====================================================================
// im2col (bf16 out)
// =====================================================================
__global__ void im2col_k(const float* __restrict__ x, __hip_bfloat16* __restrict__ A) {
    int idx = blockIdx.x * 256 + threadIdx.x;
    if (idx >= Bsz * NP * (Cch * PP * PP)) return;
    int col = idx % 768;
    int row = idx / 768;
    int b  = row / NP;
    int p  = row % NP;
    int hh = p / 14, ww = p % 14;
    int c  = col / 256;
    int rem = col % 256;
    int i = rem / 16, j = rem % 16;
    A[idx] = __float2bfloat16(
        x[(((size_t)b * Cch + c) * IMGS + hh * 16 + i) * IMGS + ww * 16 + j]);
}

// =====================================================================
// bf16 MFMA GEMM (m97 structure).
// AHEADS=1: A is head-major atth[((b*8+h)*197 + i)*96 + d] with logical
// row m=(b*197+i), col k=h*96+d. 16B chunks never straddle heads (96=12*8).
// =====================================================================
template <int OUT_BF16, int ACT, int AHEADS>
__global__ __launch_bounds__(256, 2) void gemm_bf16_k(
    const __hip_bfloat16* __restrict__ A, const __hip_bfloat16* __restrict__ W,
    const float* __restrict__ bias, void* __restrict__ outp,
    int M, int N, int K)
{
    __shared__ char As[8192];
    __shared__ char Bs[8192];
    const int tid  = threadIdx.x;
    const int lane = tid & 63;
    const int w    = tid >> 6;
    const int m0 = blockIdx.x * 128, n0 = blockIdx.y * 128;
    const int wm = (w & 1) * 64, wn = (w >> 1) * 64;

    const int q0 = w * 64 + lane, q1 = q0 + 256;
    const int r0 = q0 >> 2, r1 = q1 >> 2;
    const int c0 = (q0 & 3) ^ ((r0 >> 1) & 3);
    const int c1 = (q1 & 3) ^ ((r1 >> 1) & 3);
    int am0 = m0 + r0; if (am0 > M - 1) am0 = M - 1;
    int am1 = m0 + r1; if (am1 > M - 1) am1 = M - 1;
    const __hip_bfloat16* ag0;
    const __hip_bfloat16* ag1;
    int ab0 = 0, ab1 = 0;
    if (AHEADS == 0) {
        ag0 = A + (size_t)am0 * K + c0 * 8;
        ag1 = A + (size_t)am1 * K + c1 * 8;
    } else {
        int b0 = am0 / 197, i0 = am0 - b0 * 197;
        int b1 = am1 / 197, i1 = am1 - b1 * 197;
        ab0 = b0 * 8 * 18912 + i0 * 96;   // + h*18912 + dd*8 per iter
        ab1 = b1 * 8 * 18912 + i1 * 96;
        ag0 = A; ag1 = A;
    }
    const __hip_bfloat16* bg0 = W + (size_t)(n0 + r0) * K + c0 * 8;
    const __hip_bfloat16* bg1 = W + (size_t)(n0 + r1) * K + c1 * 8;
    char* const asd = As + w * 1024;
    char* const bsd = Bs + w * 1024;

    const int frow = lane & 15, fquad = lane >> 4;
    const int swz = (fquad ^ ((frow >> 1) & 3)) * 16;
    const char* ar = As + (wm + frow) * 64 + swz;
    const char* br = Bs + (wn + frow) * 64 + swz;

    f32x4 acc[4][4] = {};

#pragma unroll 1
    for (int k0 = 0; k0 < K; k0 += 32) {
        if (AHEADS == 0) {
            async_cp16(ag0 + k0, asd);
            async_cp16(ag1 + k0, asd + 4096);
        } else {
            int kc0 = c0 + (k0 >> 3), kc1 = c1 + (k0 >> 3);
            int h0 = kc0 / 12, dd0 = kc0 - h0 * 12;
            int h1 = kc1 / 12, dd1 = kc1 - h1 * 12;
            async_cp16(ag0 + ab0 + h0 * 18912 + dd0 * 8, asd);
            async_cp16(ag1 + ab1 + h1 * 18912 + dd1 * 8, asd + 4096);
        }
        async_cp16(bg0 + k0, bsd);
        async_cp16(bg1 + k0, bsd + 4096);
        __syncthreads();
        short8 af[4], bf[4];
#pragma unroll
        for (int i = 0; i < 4; i++) af[i] = *(const short8*)(ar + i * 1024);
#pragma unroll
        for (int j = 0; j < 4; j++) bf[j] = *(const short8*)(br + j * 1024);
#pragma unroll
        for (int i = 0; i < 4; i++)
#pragma unroll
            for (int j = 0; j < 4; j++)
                acc[i][j] = __builtin_amdgcn_mfma_f32_16x16x32_bf16(af[i], bf[j], acc[i][j], 0, 0, 0);
        __syncthreads();
    }

#pragma unroll
    for (int i = 0; i < 4; i++) {
#pragma unroll
        for (int j = 0; j < 4; j++) {
#pragma unroll
            for (int r = 0; r < 4; r++) {
                int row = m0 + wm + i * 16 + fquad * 4 + r;
                int col = n0 + wn + j * 16 + frow;
                if (row < M) {
                    float v = acc[i][j][r] + bias[col];
                    if (ACT == 1) v = 0.5f * v * (1.0f + erff(v * 0.70710678118654752f));
                    if (OUT_BF16) ((__hip_bfloat16*)outp)[(size_t)row * N + col] = __float2bfloat16(v);
                    else          ((float*)outp)[(size_t)row * N + col] = v;
                }
            }
        }
    }
}

// =====================================================================
// assemble
// =====================================================================
__global__ void assemble_k(const float* __restrict__ ptmp, const float* __restrict__ cls,
                           const float* __restrict__ pos, float* __restrict__ X,
                           __hip_bfloat16* __restrict__ Xb) {
    int idx = blockIdx.x * 256 + threadIdx.x;
    if (idx >= Bsz * Nn * E) return;
    int e = idx % E;
    int r = idx / E;
    int n = r % Nn, b = r / Nn;
    float v = (n == 0) ? cls[e] : ptmp[((size_t)b * NP + (n - 1)) * E + e];
    v += pos[(size_t)n * E + e];
    X[idx] = v;
    Xb[idx] = __float2bfloat16(v);
}

// =====================================================================
// V transpose: Vtg[bh][d][j] (row stride 232 shorts), padded cols zeroed
// =====================================================================
__global__ void vtr_k(const __hip_bfloat16* __restrict__ qkv, __hip_bfloat16* __restrict__ Vtg) {
    __shared__ short T[64][104];
    const int tid = threadIdx.x;
    const int bh = blockIdx.y, jc = blockIdx.x;
    const int b = bh >> 3, h = bh & 7;
    const int j0 = jc * 64;
#pragma unroll
    for (int it = 0; it < 3; it++) {
        int idx = it * 256 + tid;
        int jl = idx / 12, off = (idx % 12) * 8;
        int j = j0 + jl;
        short8 v = {0, 0, 0, 0, 0, 0, 0, 0};
        if (j <= 196)
            v = *(const short8*)(qkv + (size_t)(b * Nn + j) * 2304 + 1536 + h * 96 + off);
        *(short8*)(&T[jl][off]) = v;
    }
    __syncthreads();
#pragma unroll
    for (int it = 0; it < 3; it++) {
        int idx = it * 256 + tid;
        int d = idx >> 3, c = idx & 7;
        int col = j0 + c * 8;
        if (col < 232) {
            short8 v;
#pragma unroll
            for (int k = 0; k < 8; k++) v[k] = T[c * 8 + k][d];
            *(short8*)(Vtg + ((size_t)bh * 96 + d) * 232 + col) = v;
        }
    }
}

// =====================================================================
// Fused attention, one block per (b,h). 4 waves, 13 m-tiles interleaved.
// Phase 1: K slab staged once in LDS (208B rows, conflict-light) ->
//          S = QK^T, softmax, P stashed as bf16 A-frags in registers.
// Phase 2: V^T slab DMA'd into same LDS -> O = P V -> dense head-major
//          store atth[bh][i][96] (block-private slab, no partial-line
//          sharing across blocks).
// =====================================================================
__global__ __launch_bounds__(256, 1) void fattn_k(
    const __hip_bfloat16* __restrict__ qkv,
    const __hip_bfloat16* __restrict__ Vtg,
    __hip_bfloat16* __restrict__ atth)
{
    __shared__ __align__(16) char SL[44544 + 4 * 1280];  // K/Vt overlay + per-wave Ps
    char* const Ps = SL + 44544;
    const int tid = threadIdx.x, lane = tid & 63, w = tid >> 6;
    const int bh = blockIdx.x;
    const int b = bh >> 3, h = bh & 7;
    const int frow = lane & 15, quad = lane >> 4;

    // ---- stage K slab: rows j=0..196, 96 cols, LDS row stride 208B ----
#pragma unroll
    for (int it = 0; it < 10; it++) {
        int c = it * 256 + tid;
        if (c < 197 * 12) {
            int j = c / 12, cc = c % 12;
            short8 v = *(const short8*)(qkv + ((size_t)(b * 197 + j)) * 2304 + 768 + h * 96 + cc * 8);
            *(short8*)(SL + j * 208 + cc * 16) = v;
        }
    }
    __syncthreads();

    // ---- phase 1: S, softmax, P-frags ----
    short8 pf[4][7];
#pragma unroll 1
    for (int t = 0; t < 4; t++) {
        const int mt = w + 4 * t;
        if (mt >= 13) break;
        const int qi = min(mt * 16 + frow, 196);
        const __hip_bfloat16* qrow = qkv + ((size_t)(b * 197 + qi)) * 2304 + h * 96 + quad * 8;
        short8 qf[3];
#pragma unroll
        for (int kc = 0; kc < 3; kc++) qf[kc] = *(const short8*)(qrow + kc * 32);

        f32x4 sacc[13];
#pragma unroll
        for (int nt = 0; nt < 13; nt++) sacc[nt] = (f32x4){0.f, 0.f, 0.f, 0.f};
#pragma unroll
        for (int nt = 0; nt < 13; nt++) {
#pragma unroll
            for (int kc = 0; kc < 3; kc++) {
                short8 kf = *(const short8*)(SL + (nt * 16 + frow) * 208 + (kc * 32 + quad * 8) * 2);
                sacc[nt] = __builtin_amdgcn_mfma_f32_16x16x32_bf16(qf[kc], kf, sacc[nt], 0, 0, 0);
            }
        }

        // softmax over cols (col = nt*16+frow across 16-lane groups)
        float mx[4] = {-1e30f, -1e30f, -1e30f, -1e30f};
#pragma unroll
        for (int nt = 0; nt < 13; nt++) {
            bool masked = (nt == 12) && (frow >= 5);
#pragma unroll
            for (int r = 0; r < 4; r++) {
                float v = masked ? -1e30f : sacc[nt][r];
                sacc[nt][r] = v;
                mx[r] = fmaxf(mx[r], v);
            }
        }
#pragma unroll
        for (int m = 1; m <= 8; m <<= 1)
#pragma unroll
            for (int r = 0; r < 4; r++) mx[r] = fmaxf(mx[r], __shfl_xor(mx[r], m));
        float sm[4] = {0.f, 0.f, 0.f, 0.f};
#pragma unroll
        for (int nt = 0; nt < 13; nt++) {
            bool masked = (nt == 12) && (frow >= 5);
#pragma unroll
            for (int r = 0; r < 4; r++) {
                float e = masked ? 0.f : __expf(sacc[nt][r] - mx[r]);
                sacc[nt][r] = e;
                sm[r] += e;
            }
        }
#pragma unroll
        for (int m = 1; m <= 8; m <<= 1)
#pragma unroll
            for (int r = 0; r < 4; r++) sm[r] += __shfl_xor(sm[r], m);
        float inv[4];
#pragma unroll
        for (int r = 0; r < 4; r++) inv[r] = SCALE / sm[r];

        // P -> A-layout frags via per-wave LDS round trip
        char* const myPs = Ps + w * 1280;
#pragma unroll
        for (int kc = 0; kc < 7; kc++) {
#pragma unroll
            for (int tt = 0; tt < 2; tt++) {
                int t2 = kc * 2 + tt;
#pragma unroll
                for (int r = 0; r < 4; r++) {
                    float pv = (t2 < 13) ? sacc[t2][r] * inv[r] : 0.f;
                    *(__hip_bfloat16*)(myPs + (quad * 4 + r) * 80 + (tt * 16 + frow) * 2) =
                        __float2bfloat16(pv);
                }
            }
            pf[t][kc] = *(const short8*)(myPs + frow * 80 + quad * 16);
        }
    }
    __syncthreads();

    // ---- stage V^T slab (contiguous padded 96x464B) over K region ----
    {
        const char* src = (const char*)(Vtg + (size_t)bh * 96 * 232);
#pragma unroll
        for (int i = 0; i < 11; i++) {
            int c = i * 256 + w * 64 + lane;
            if (c < 96 * 29)
                async_cp16(src + (size_t)c * 16, SL + (size_t)(i * 256 + w * 64) * 16);
        }
    }
    __syncthreads();

    // ---- phase 2: O = P V, dense head-major store ----
#pragma unroll 1
    for (int t = 0; t < 4; t++) {
        const int mt = w + 4 * t;
        if (mt >= 13) break;
        f32x4 oacc[6];
#pragma unroll
        for (int dt = 0; dt < 6; dt++) oacc[dt] = (f32x4){0.f, 0.f, 0.f, 0.f};
#pragma unroll
        for (int kc = 0; kc < 7; kc++) {
#pragma unroll
            for (int dt = 0; dt < 6; dt++) {
                short8 vf = *(const short8*)(SL + (size_t)(dt * 16 + frow) * 464 +
                                             (kc * 32 + quad * 8) * 2);
                oacc[dt] = __builtin_amdgcn_mfma_f32_16x16x32_bf16(pf[t][kc], vf, oacc[dt], 0, 0, 0);
            }
        }
#pragma unroll
        for (int dt = 0; dt < 6; dt++)
#pragma unroll
            for (int r = 0; r < 4; r++) {
                int i = mt * 16 + quad * 4 + r;
                if (i < 197)
                    atth[((size_t)bh * 197 + i) * 96 + dt * 16 + frow] =
                        __float2bfloat16(oacc[dt][r]);
            }
    }
}

// =====================================================================
// x = LN(x + t); writes f32 X in place and bf16 shadow Xb
// =====================================================================
__global__ void add_ln_k(float* __restrict__ X, const float* __restrict__ T,
                         const float* __restrict__ g, const float* __restrict__ bb,
                         __hip_bfloat16* __restrict__ Xb) {
    const size_t row = blockIdx.x;
    float* xr = X + row * E;
    const float* tr = T + row * E;
    const int t = threadIdx.x;
    __shared__ float red[4];
    float v[3];
    float s = 0.f;
#pragma unroll
    for (int i = 0; i < 3; i++) {
        v[i] = xr[t + i * 256] + tr[t + i * 256];
        s += v[i];
    }
    for (int off = 32; off > 0; off >>= 1) s += __shfl_down(s, off);
    int wid = t >> 6, lane = t & 63;
    if (lane == 0) red[wid] = s;
    __syncthreads();
    if (t == 0) red[0] = red[0] + red[1] + red[2] + red[3];
    __syncthreads();
    float mean = red[0] / 768.f;
    __syncthreads();
    float s2 = 0.f;
#pragma unroll
    for (int i = 0; i < 3; i++) {
        float dl = v[i] - mean;
        s2 += dl * dl;
    }
    for (int off = 32; off > 0; off >>= 1) s2 += __shfl_down(s2, off);
    if (lane == 0) red[wid] = s2;
    __syncthreads();
    if (t == 0) red[0] = red[0] + red[1] + red[2] + red[3];
    __syncthreads();
    float rs = rsqrtf(red[0] / 768.f + EPSc);
#pragma unroll
    for (int i = 0; i < 3; i++) {
        int e = t + i * 256;
        float o = (v[i] - mean) * rs * g[e] + bb[e];
        xr[e] = o;
        Xb[row * E + e] = __float2bfloat16(o);
    }
}

// =====================================================================
// mean pool over N + LN -> pooled
// =====================================================================
__global__ void pool_ln_k(const float* __restrict__ X, const float* __restrict__ g,
                          const float* __restrict__ bb, float* __restrict__ pooled) {
    __shared__ float red[4];
    const int b = blockIdx.x, t = threadIdx.x;
    float loc[3];
#pragma unroll
    for (int i = 0; i < 3; i++) {
        int e = t + i * 256;
        float s = 0.f;
        for (int n = 0; n < Nn; n++) s += X[((size_t)(b * Nn + n)) * E + e];
        loc[i] = s / (float)Nn;
    }
    float s = loc[0] + loc[1] + loc[2];
    for (int off = 32; off > 0; off >>= 1) s += __shfl_down(s, off);
    int wid = t >> 6, lane = t & 63;
    if (lane == 0) red[wid] = s;
    __syncthreads();
    if (t == 0) red[0] = red[0] + red[1] + red[2] + red[3];
    __syncthreads();
    float mean = red[0] / 768.f;
    __syncthreads();
    float s2 = 0.f;
#pragma unroll
    for (int i = 0; i < 3; i++) {
        float dl = loc[i] - mean;
        s2 += dl * dl;
    }
    for (int off = 32; off > 0; off >>= 1) s2 += __shfl_down(s2, off);
    if (lane == 0) red[wid] = s2;
    __syncthreads();
    if (t == 0) red[0] = red[0] + red[1] + red[2] + red[3];
    __syncthreads();
    float rs = rsqrtf(red[0] / 768.f + EPSc);
#pragma unroll
    for (int i = 0; i < 3; i++) {
        int e = t + i * 256;
        pooled[(size_t)b * E + e] = (loc[i] - mean) * rs * g[e] + bb[e];
    }
}

// =====================================================================
// head matvec
// =====================================================================
__global__ void head_k(const float* __restrict__ pooled, const float* __restrict__ hw,
                       const float* __restrict__ hb, float* __restrict__ out) {
    __shared__ float ps[768];
    const int b = blockIdx.y;
    const int s = blockIdx.x;
    const int t = threadIdx.x, lane = t & 63, w = t >> 6;
    for (int e = t; e < 768; e += 256) ps[e] = pooled[(size_t)b * E + e];
    __syncthreads();
    float pl[12];
#pragma unroll
    for (int j = 0; j < 12; j++) pl[j] = ps[j * 64 + lane];
    for (int i = 0; i < 10; i++) {
        int o = s * 40 + w * 10 + i;
        const float* wr = hw + (size_t)o * 768;
        float acc = 0.f;
#pragma unroll
        for (int j = 0; j < 12; j++) acc += pl[j] * wr[j * 64 + lane];
        for (int off = 32; off > 0; off >>= 1) acc += __shfl_down(acc, off);
        if (lane == 0) out[(size_t)b * NC + o] = acc + hb[o];
    }
}

// =====================================================================
extern "C" void kernel_launch(void* const* d_in, const int* in_sizes, int n_in,
                              void* d_out, int out_size, void* d_ws, size_t ws_size,
                              hipStream_t stream) {
    const float* x        = (const float*)d_in[0];
    const float* conv_w   = (const float*)d_in[1];
    const float* conv_b   = (const float*)d_in[2];
    const float* cls_tok  = (const float*)d_in[3];
    const float* pos_emb  = (const float*)d_in[4];
    const float* qkv_w    = (const float*)d_in[5];
    const float* qkv_b    = (const float*)d_in[6];
    const float* proj_w   = (const float*)d_in[7];
    const float* proj_b   = (const float*)d_in[8];
    const float* ln1_g    = (const float*)d_in[9];
    const float* ln1_b    = (const float*)d_in[10];
    const float* mlp_w1   = (const float*)d_in[11];
    const float* mlp_b1   = (const float*)d_in[12];
    const float* mlp_w2   = (const float*)d_in[13];
    const float* mlp_b2   = (const float*)d_in[14];
    const float* ln2_g    = (const float*)d_in[15];
    const float* ln2_b    = (const float*)d_in[16];
    const float* hln_g    = (const float*)d_in[17];
    const float* hln_b    = (const float*)d_in[18];
    const float* head_w   = (const float*)d_in[19];
    const float* head_b   = (const float*)d_in[20];
    float* out = (float*)d_out;

    const int M = Bsz * Nn;  // 6304

    // ---- workspace carve-up ----
    char* p = (char*)d_ws;
    __hip_bfloat16* Xb   = (__hip_bfloat16*)p;  p += (size_t)M * E * 2;
    float*          X    = (float*)p;           p += (size_t)M * E * 4;
    __hip_bfloat16* qwb  = (__hip_bfloat16*)p;  p += (size_t)3 * E * E * 2;
    __hip_bfloat16* pwb  = (__hip_bfloat16*)p;  p += (size_t)E * E * 2;
    __hip_bfloat16* w1b  = (__hip_bfloat16*)p;  p += (size_t)FF * E * 2;
    __hip_bfloat16* w2b  = (__hip_bfloat16*)p;  p += (size_t)E * FF * 2;
    __hip_bfloat16* cwb  = (__hip_bfloat16*)p;  p += (size_t)E * E * 2;
    __hip_bfloat16* atth = (__hip_bfloat16*)p;  p += (size_t)M * E * 2;  // head-major [bh][197][96]
    float*          pool = (float*)p;           p += (size_t)Bsz * E * 4;
    char* R = p;
    // live set A (attention): qkvb [29,048,832 B] + Vtg [11,403,264 B]
    // live set B (patch/MLP): Hb [38,731,776 B] + Ctmp [19,365,888 B]
    __hip_bfloat16* qkvb = (__hip_bfloat16*)R;
    __hip_bfloat16* Vtg  = (__hip_bfloat16*)(R + 29048832);
    __hip_bfloat16* Hb   = (__hip_bfloat16*)R;
    float*          Ctmp = (float*)(R + 40452096);
    __hip_bfloat16* imb  = (__hip_bfloat16*)R;

    // ---- patch embed ----
    {
        f2b_k<<<(E * E / 4 + 255) / 256, 256, 0, stream>>>(conv_w, cwb, E * E / 4);
        int tot = Bsz * NP * 768;
        im2col_k<<<(tot + 255) / 256, 256, 0, stream>>>(x, imb);
        dim3 g(49, 6);
        gemm_bf16_k<0, 0, 0><<<g, 256, 0, stream>>>(imb, cwb, conv_b, Ctmp, Bsz * NP, E, E);
        int tot2 = Bsz * Nn * E;
        assemble_k<<<(tot2 + 255) / 256, 256, 0, stream>>>(Ctmp, cls_tok, pos_emb, X, Xb);
    }

    const int MB = (M + 127) / 128;  // 50
    const int cn0 = 3 * E * E / 4, cn1 = E * E / 4, cn2 = FF * E / 4, cn3 = E * FF / 4;
    const int cgrid = (cn0 + cn1 + cn2 + cn3 + 255) / 256;

    // ---- transformer layers ----
    for (int l = 0; l < Lnum; l++) {
        const float* qw = qkv_w + (size_t)l * 3 * E * E;
        const float* qb = qkv_b + (size_t)l * 3 * E;
        const float* pw = proj_w + (size_t)l * E * E;
        const float* pb = proj_b + (size_t)l * E;
        const float* g1 = ln1_g + (size_t)l * E;
        const float* b1 = ln1_b + (size_t)l * E;
        const float* w1 = mlp_w1 + (size_t)l * FF * E;
        const float* bb1 = mlp_b1 + (size_t)l * FF;
        const float* w2 = mlp_w2 + (size_t)l * E * FF;
        const float* bb2 = mlp_b2 + (size_t)l * E;
        const float* g2 = ln2_g + (size_t)l * E;
        const float* b2 = ln2_b + (size_t)l * E;

        // convert all 4 weight tensors in one dispatch
        f2b4_k<<<cgrid, 256, 0, stream>>>(qw, pw, w1, w2, qwb, pwb, w1b, w2b,
                                          cn0, cn1, cn2, cn3);

        // qkv = Xb @ qwb^T -> bf16 [M, 2304]
        gemm_bf16_k<1, 0, 0><<<dim3(MB, 18), 256, 0, stream>>>(Xb, qwb, qb, qkvb, M, 3 * E, E);
        // V transpose into Vtg
        vtr_k<<<dim3(4, Bsz * HEADS), 256, 0, stream>>>(qkvb, Vtg);
        // fused attention -> atth (head-major)
        fattn_k<<<Bsz * HEADS, 256, 0, stream>>>(qkvb, Vtg, atth);
        // proj (A head-major) -> f32 Ctmp
        gemm_bf16_k<0, 0, 1><<<dim3(MB, 6), 256, 0, stream>>>(atth, pwb, pb, Ctmp, M, E, E);
        add_ln_k<<<M, 256, 0, stream>>>(X, Ctmp, g1, b1, Xb);
        // MLP1 + gelu -> bf16 Hb
        gemm_bf16_k<1, 1, 0><<<dim3(MB, 24), 256, 0, stream>>>(Xb, w1b, bb1, Hb, M, FF, E);
        // MLP2 -> f32 Ctmp
        gemm_bf16_k<0, 0, 0><<<dim3(MB, 6), 256, 0, stream>>>(Hb, w2b, bb2, Ctmp, M, E, FF);
        add_ln_k<<<M, 256, 0, stream>>>(X, Ctmp, g2, b2, Xb);
    }

    // ---- head ----
    pool_ln_k<<<Bsz, 256, 0, stream>>>(X, hln_g, hln_b, pool);
    head_k<<<dim3(25, Bsz), 256, 0, stream>>>(pool, head_w, head_b, out);
}

// Round 5
// 1976.514 us; speedup vs baseline: 7.0153x; 1.0308x over previous
//
#include <hip/hip_runtime.h>
#include <hip/hip_bf16.h>
#include <math.h>

// ---- problem constants ----
constexpr int Bsz = 32, Cch = 3, IMGS = 224, PP = 16;
constexpr int E = 768, HEADS = 8, Lnum = 6, NC = 1000;
constexpr int HD = 96;
constexpr int NP = 196;
constexpr int Nn = 197;
constexpr int FF = 3072;
constexpr float SCALE = 0.10206207261596575f;  // 96^-0.5
constexpr float EPSc  = 1e-5f;

using short8 = __attribute__((ext_vector_type(8))) short;
using f32x4  = __attribute__((ext_vector_type(4))) float;

__device__ __forceinline__ void async_cp16(const void* g, void* l) {
    __builtin_amdgcn_global_load_lds((const __attribute__((address_space(1))) void*)g,
                                     (__attribute__((address_space(3))) void*)l, 16, 0, 0);
}

// =====================================================================
// f32 -> bf16 convert (single tensor)
// =====================================================================
__global__ void f2b_k(const float* __restrict__ in, __hip_bfloat16* __restrict__ out, int n4) {
    int i = blockIdx.x * 256 + threadIdx.x;
    if (i >= n4) return;
    const float4 v = ((const float4*)in)[i];
    size_t o = (size_t)i * 4;
    out[o + 0] = __float2bfloat16(v.x);
    out[o + 1] = __float2bfloat16(v.y);
    out[o + 2] = __float2bfloat16(v.z);
    out[o + 3] = __float2bfloat16(v.w);
}

// =====================================================================
// fused 4-tensor f32 -> bf16 (one dispatch per layer's weights)
// =====================================================================
__global__ void f2b4_k(const float* __restrict__ s0, const float* __restrict__ s1,
                       const float* __restrict__ s2, const float* __restrict__ s3,
                       __hip_bfloat16* __restrict__ d0, __hip_bfloat16* __restrict__ d1,
                       __hip_bfloat16* __restrict__ d2, __hip_bfloat16* __restrict__ d3,
                       int n0, int n1, int n2, int n3) {
    int i = blockIdx.x * 256 + threadIdx.x;
    const float* s; __hip_bfloat16* d; int base;
    if (i < n0)                { s = s0; d = d0; base = 0; }
    else if (i < n0 + n1)      { s = s1; d = d1; base = n0; }
    else if (i < n0 + n1 + n2) { s = s2; d = d2; base = n0 + n1; }
    else if (i < n0 + n1 + n2 + n3) { s = s3; d = d3; base = n0 + n1 + n2; }
    else return;
    int k = i - base;
    const float4 v = ((const float4*)s)[k];
    size_t o = (size_t)k * 4;
    d[o + 0] = __float2bfloat16(v.x);
    d[o + 1] = __float2bfloat16(v.y);
    d[o + 2] = __float2bfloat16(v.z);
    d[o + 3] = __float2bfloat16(v.w);
}

// =====================================================================
// im2col (bf16 out)
// =====================================================================
__global__ void im2col_k(const float* __restrict__ x, __hip_bfloat16* __restrict__ A) {
    int idx = blockIdx.x * 256 + threadIdx.x;
    if (idx >= Bsz * NP * (Cch * PP * PP)) return;
    int col = idx % 768;
    int row = idx / 768;
    int b  = row / NP;
    int p  = row % NP;
    int hh = p / 14, ww = p % 14;
    int c  = col / 256;
    int rem = col % 256;
    int i = rem / 16, j = rem % 16;
    A[idx] = __float2bfloat16(
        x[(((size_t)b * Cch + c) * IMGS + hh * 16 + i) * IMGS + ww * 16 + j]);
}

// =====================================================================
// bf16 MFMA GEMM. TM = 128 (4 waves x 64x64) or 64 (4 waves x 64x32,
// 64-row A tile -> 2x the blocks for small-N GEMMs).
// AHEADS=1: A is head-major atth[((b*8+h)*197+i)*96+d], m=(b*197+i), k=h*96+d.
// __launch_bounds__(256,4): 4 blocks/CU so cross-block overlap hides the
// per-iteration barrier drain (VGPR+AGPR ~120 <= 128).
// =====================================================================
template <int TM, int OUT_BF16, int ACT, int AHEADS>
__global__ __launch_bounds__(256, 4) void gemm_bf16_k(
    const __hip_bfloat16* __restrict__ A, const __hip_bfloat16* __restrict__ W,
    const float* __restrict__ bias, void* __restrict__ outp,
    int M, int N, int K)
{
    constexpr int NA = TM / 64;            // A chunks per thread (2 for 128, 1 for 64)
    constexpr int JN = (TM == 128) ? 4 : 2; // b-frags per wave
    __shared__ char As[TM * 64];
    __shared__ char Bs[8192];
    const int tid  = threadIdx.x;
    const int lane = tid & 63;
    const int w    = tid >> 6;
    const int m0 = blockIdx.x * TM, n0 = blockIdx.y * 128;
    const int wm = (TM == 128) ? (w & 1) * 64 : 0;
    const int wn = (TM == 128) ? (w >> 1) * 64 : w * 32;

    // ---- A staging pointers (chunk q -> row q>>2, swizzled chunk) ----
    const __hip_bfloat16* agv[NA];
    int abv[NA], acv[NA];
#pragma unroll
    for (int i = 0; i < NA; i++) {
        int q = tid + i * 256;
        int r = q >> 2;
        int c = (q & 3) ^ ((r >> 1) & 3);
        int am = m0 + r; if (am > M - 1) am = M - 1;
        if (AHEADS == 0) {
            agv[i] = A + (size_t)am * K + c * 8;
            abv[i] = 0; acv[i] = 0;
        } else {
            int b_ = am / 197, i_ = am - b_ * 197;
            abv[i] = b_ * 8 * 18912 + i_ * 96;
            acv[i] = c;
            agv[i] = A;
        }
    }
    // ---- B staging pointers (128 rows always) ----
    const int q0 = tid, q1 = tid + 256;
    const int rb0 = q0 >> 2, rb1 = q1 >> 2;
    const int cb0 = (q0 & 3) ^ ((rb0 >> 1) & 3);
    const int cb1 = (q1 & 3) ^ ((rb1 >> 1) & 3);
    const __hip_bfloat16* bg0 = W + (size_t)(n0 + rb0) * K + cb0 * 8;
    const __hip_bfloat16* bg1 = W + (size_t)(n0 + rb1) * K + cb1 * 8;
    char* const asd = As + w * 1024;   // wave-uniform LDS dest bases
    char* const bsd = Bs + w * 1024;

    // ---- fragment read bases ----
    const int frow = lane & 15, fquad = lane >> 4;
    const int swz = (fquad ^ ((frow >> 1) & 3)) * 16;
    const char* ar = As + (wm + frow) * 64 + swz;
    const char* br = Bs + (wn + frow) * 64 + swz;

    f32x4 acc[4][JN] = {};

#pragma unroll 1
    for (int k0 = 0; k0 < K; k0 += 32) {
#pragma unroll
        for (int i = 0; i < NA; i++) {
            if (AHEADS == 0) {
                async_cp16(agv[i] + k0, asd + i * 4096);
            } else {
                int kc = acv[i] + (k0 >> 3);
                int h = kc / 12, dd = kc - h * 12;
                async_cp16(agv[i] + abv[i] + h * 18912 + dd * 8, asd + i * 4096);
            }
        }
        async_cp16(bg0 + k0, bsd);
        async_cp16(bg1 + k0, bsd + 4096);
        __syncthreads();
        short8 af[4], bf[JN];
#pragma unroll
        for (int i = 0; i < 4; i++) af[i] = *(const short8*)(ar + i * 1024);
#pragma unroll
        for (int j = 0; j < JN; j++) bf[j] = *(const short8*)(br + j * 1024);
#pragma unroll
        for (int i = 0; i < 4; i++)
#pragma unroll
            for (int j = 0; j < JN; j++)
                acc[i][j] = __builtin_amdgcn_mfma_f32_16x16x32_bf16(af[i], bf[j], acc[i][j], 0, 0, 0);
        __syncthreads();
    }

    // ---- epilogue (C/D layout: col=lane&15, row=(lane>>4)*4+reg) ----
#pragma unroll
    for (int i = 0; i < 4; i++) {
#pragma unroll
        for (int j = 0; j < JN; j++) {
#pragma unroll
            for (int r = 0; r < 4; r++) {
                int row = m0 + wm + i * 16 + fquad * 4 + r;
                int col = n0 + wn + j * 16 + frow;
                if (row < M) {
                    float v = acc[i][j][r] + bias[col];
                    if (ACT == 1) v = 0.5f * v * (1.0f + erff(v * 0.70710678118654752f));
                    if (OUT_BF16) ((__hip_bfloat16*)outp)[(size_t)row * N + col] = __float2bfloat16(v);
                    else          ((float*)outp)[(size_t)row * N + col] = v;
                }
            }
        }
    }
}

// =====================================================================
// assemble
// =====================================================================
__global__ void assemble_k(const float* __restrict__ ptmp, const float* __restrict__ cls,
                           const float* __restrict__ pos, float* __restrict__ X,
                           __hip_bfloat16* __restrict__ Xb) {
    int idx = blockIdx.x * 256 + threadIdx.x;
    if (idx >= Bsz * Nn * E) return;
    int e = idx % E;
    int r = idx / E;
    int n = r % Nn, b = r / Nn;
    float v = (n == 0) ? cls[e] : ptmp[((size_t)b * NP + (n - 1)) * E + e];
    v += pos[(size_t)n * E + e];
    X[idx] = v;
    Xb[idx] = __float2bfloat16(v);
}

// =====================================================================
// V transpose: Vtg[bh][d][j] (row stride 232 shorts), padded cols zeroed
// =====================================================================
__global__ void vtr_k(const __hip_bfloat16* __restrict__ qkv, __hip_bfloat16* __restrict__ Vtg) {
    __shared__ short T[64][104];
    const int tid = threadIdx.x;
    const int bh = blockIdx.y, jc = blockIdx.x;
    const int b = bh >> 3, h = bh & 7;
    const int j0 = jc * 64;
#pragma unroll
    for (int it = 0; it < 3; it++) {
        int idx = it * 256 + tid;
        int jl = idx / 12, off = (idx % 12) * 8;
        int j = j0 + jl;
        short8 v = {0, 0, 0, 0, 0, 0, 0, 0};
        if (j <= 196)
            v = *(const short8*)(qkv + (size_t)(b * Nn + j) * 2304 + 1536 + h * 96 + off);
        *(short8*)(&T[jl][off]) = v;
    }
    __syncthreads();
#pragma unroll
    for (int it = 0; it < 3; it++) {
        int idx = it * 256 + tid;
        int d = idx >> 3, c = idx & 7;
        int col = j0 + c * 8;
        if (col < 232) {
            short8 v;
#pragma unroll
            for (int k = 0; k < 8; k++) v[k] = T[c * 8 + k][d];
            *(short8*)(Vtg + ((size_t)bh * 96 + d) * 232 + col) = v;
        }
    }
}

// =====================================================================
// Fused attention, one block per (b,h) — unchanged from round 4.
// =====================================================================
__global__ __launch_bounds__(256, 1) void fattn_k(
    const __hip_bfloat16* __restrict__ qkv,
    const __hip_bfloat16* __restrict__ Vtg,
    __hip_bfloat16* __restrict__ atth)
{
    __shared__ __align__(16) char SL[44544 + 4 * 1280];
    char* const Ps = SL + 44544;
    const int tid = threadIdx.x, lane = tid & 63, w = tid >> 6;
    const int bh = blockIdx.x;
    const int b = bh >> 3, h = bh & 7;
    const int frow = lane & 15, quad = lane >> 4;

#pragma unroll
    for (int it = 0; it < 10; it++) {
        int c = it * 256 + tid;
        if (c < 197 * 12) {
            int j = c / 12, cc = c % 12;
            short8 v = *(const short8*)(qkv + ((size_t)(b * 197 + j)) * 2304 + 768 + h * 96 + cc * 8);
            *(short8*)(SL + j * 208 + cc * 16) = v;
        }
    }
    __syncthreads();

    short8 pf[4][7];
#pragma unroll 1
    for (int t = 0; t < 4; t++) {
        const int mt = w + 4 * t;
        if (mt >= 13) break;
        const int qi = min(mt * 16 + frow, 196);
        const __hip_bfloat16* qrow = qkv + ((size_t)(b * 197 + qi)) * 2304 + h * 96 + quad * 8;
        short8 qf[3];
#pragma unroll
        for (int kc = 0; kc < 3; kc++) qf[kc] = *(const short8*)(qrow + kc * 32);

        f32x4 sacc[13];
#pragma unroll
        for (int nt = 0; nt < 13; nt++) sacc[nt] = (f32x4){0.f, 0.f, 0.f, 0.f};
#pragma unroll
        for (int nt = 0; nt < 13; nt++) {
#pragma unroll
            for (int kc = 0; kc < 3; kc++) {
                short8 kf = *(const short8*)(SL + (nt * 16 + frow) * 208 + (kc * 32 + quad * 8) * 2);
                sacc[nt] = __builtin_amdgcn_mfma_f32_16x16x32_bf16(qf[kc], kf, sacc[nt], 0, 0, 0);
            }
        }

        float mx[4] = {-1e30f, -1e30f, -1e30f, -1e30f};
#pragma unroll
        for (int nt = 0; nt < 13; nt++) {
            bool masked = (nt == 12) && (frow >= 5);
#pragma unroll
            for (int r = 0; r < 4; r++) {
                float v = masked ? -1e30f : sacc[nt][r];
                sacc[nt][r] = v;
                mx[r] = fmaxf(mx[r], v);
            }
        }
#pragma unroll
        for (int m = 1; m <= 8; m <<= 1)
#pragma unroll
            for (int r = 0; r < 4; r++) mx[r] = fmaxf(mx[r], __shfl_xor(mx[r], m));
        float sm[4] = {0.f, 0.f, 0.f, 0.f};
#pragma unroll
        for (int nt = 0; nt < 13; nt++) {
            bool masked = (nt == 12) && (frow >= 5);
#pragma unroll
            for (int r = 0; r < 4; r++) {
                float e = masked ? 0.f : __expf(sacc[nt][r] - mx[r]);
                sacc[nt][r] = e;
                sm[r] += e;
            }
        }
#pragma unroll
        for (int m = 1; m <= 8; m <<= 1)
#pragma unroll
            for (int r = 0; r < 4; r++) sm[r] += __shfl_xor(sm[r], m);
        float inv[4];
#pragma unroll
        for (int r = 0; r < 4; r++) inv[r] = SCALE / sm[r];

        char* const myPs = Ps + w * 1280;
#pragma unroll
        for (int kc = 0; kc < 7; kc++) {
#pragma unroll
            for (int tt = 0; tt < 2; tt++) {
                int t2 = kc * 2 + tt;
#pragma unroll
                for (int r = 0; r < 4; r++) {
                    float pv = (t2 < 13) ? sacc[t2][r] * inv[r] : 0.f;
                    *(__hip_bfloat16*)(myPs + (quad * 4 + r) * 80 + (tt * 16 + frow) * 2) =
                        __float2bfloat16(pv);
                }
            }
            pf[t][kc] = *(const short8*)(myPs + frow * 80 + quad * 16);
        }
    }
    __syncthreads();

    {
        const char* src = (const char*)(Vtg + (size_t)bh * 96 * 232);
#pragma unroll
        for (int i = 0; i < 11; i++) {
            int c = i * 256 + w * 64 + lane;
            if (c < 96 * 29)
                async_cp16(src + (size_t)c * 16, SL + (size_t)(i * 256 + w * 64) * 16);
        }
    }
    __syncthreads();

#pragma unroll 1
    for (int t = 0; t < 4; t++) {
        const int mt = w + 4 * t;
        if (mt >= 13) break;
        f32x4 oacc[6];
#pragma unroll
        for (int dt = 0; dt < 6; dt++) oacc[dt] = (f32x4){0.f, 0.f, 0.f, 0.f};
#pragma unroll
        for (int kc = 0; kc < 7; kc++) {
#pragma unroll
            for (int dt = 0; dt < 6; dt++) {
                short8 vf = *(const short8*)(SL + (size_t)(dt * 16 + frow) * 464 +
                                             (kc * 32 + quad * 8) * 2);
                oacc[dt] = __builtin_amdgcn_mfma_f32_16x16x32_bf16(pf[t][kc], vf, oacc[dt], 0, 0, 0);
            }
        }
#pragma unroll
        for (int dt = 0; dt < 6; dt++)
#pragma unroll
            for (int r = 0; r < 4; r++) {
                int i = mt * 16 + quad * 4 + r;
                if (i < 197)
                    atth[((size_t)bh * 197 + i) * 96 + dt * 16 + frow] =
                        __float2bfloat16(oacc[dt][r]);
            }
    }
}

// =====================================================================
// x = LN(x + t); writes f32 X in place and bf16 shadow Xb
// =====================================================================
__global__ void add_ln_k(float* __restrict__ X, const float* __restrict__ T,
                         const float* __restrict__ g, const float* __restrict__ bb,
                         __hip_bfloat16* __restrict__ Xb) {
    const size_t row = blockIdx.x;
    float* xr = X + row * E;
    const float* tr = T + row * E;
    const int t = threadIdx.x;
    __shared__ float red[4];
    float v[3];
    float s = 0.f;
#pragma unroll
    for (int i = 0; i < 3; i++) {
        v[i] = xr[t + i * 256] + tr[t + i * 256];
        s += v[i];
    }
    for (int off = 32; off > 0; off >>= 1) s += __shfl_down(s, off);
    int wid = t >> 6, lane = t & 63;
    if (lane == 0) red[wid] = s;
    __syncthreads();
    if (t == 0) red[0] = red[0] + red[1] + red[2] + red[3];
    __syncthreads();
    float mean = red[0] / 768.f;
    __syncthreads();
    float s2 = 0.f;
#pragma unroll
    for (int i = 0; i < 3; i++) {
        float dl = v[i] - mean;
        s2 += dl * dl;
    }
    for (int off = 32; off > 0; off >>= 1) s2 += __shfl_down(s2, off);
    if (lane == 0) red[wid] = s2;
    __syncthreads();
    if (t == 0) red[0] = red[0] + red[1] + red[2] + red[3];
    __syncthreads();
    float rs = rsqrtf(red[0] / 768.f + EPSc);
#pragma unroll
    for (int i = 0; i < 3; i++) {
        int e = t + i * 256;
        float o = (v[i] - mean) * rs * g[e] + bb[e];
        xr[e] = o;
        Xb[row * E + e] = __float2bfloat16(o);
    }
}

// =====================================================================
// mean pool over N + LN -> pooled
// =====================================================================
__global__ void pool_ln_k(const float* __restrict__ X, const float* __restrict__ g,
                          const float* __restrict__ bb, float* __restrict__ pooled) {
    __shared__ float red[4];
    const int b = blockIdx.x, t = threadIdx.x;
    float loc[3];
#pragma unroll
    for (int i = 0; i < 3; i++) {
        int e = t + i * 256;
        float s = 0.f;
        for (int n = 0; n < Nn; n++) s += X[((size_t)(b * Nn + n)) * E + e];
        loc[i] = s / (float)Nn;
    }
    float s = loc[0] + loc[1] + loc[2];
    for (int off = 32; off > 0; off >>= 1) s += __shfl_down(s, off);
    int wid = t >> 6, lane = t & 63;
    if (lane == 0) red[wid] = s;
    __syncthreads();
    if (t == 0) red[0] = red[0] + red[1] + red[2] + red[3];
    __syncthreads();
    float mean = red[0] / 768.f;
    __syncthreads();
    float s2 = 0.f;
#pragma unroll
    for (int i = 0; i < 3; i++) {
        float dl = loc[i] - mean;
        s2 += dl * dl;
    }
    for (int off = 32; off > 0; off >>= 1) s2 += __shfl_down(s2, off);
    if (lane == 0) red[wid] = s2;
    __syncthreads();
    if (t == 0) red[0] = red[0] + red[1] + red[2] + red[3];
    __syncthreads();
    float rs = rsqrtf(red[0] / 768.f + EPSc);
#pragma unroll
    for (int i = 0; i < 3; i++) {
        int e = t + i * 256;
        pooled[(size_t)b * E + e] = (loc[i] - mean) * rs * g[e] + bb[e];
    }
}

// =====================================================================
// head matvec
// =====================================================================
__global__ void head_k(const float* __restrict__ pooled, const float* __restrict__ hw,
                       const float* __restrict__ hb, float* __restrict__ out) {
    __shared__ float ps[768];
    const int b = blockIdx.y;
    const int s = blockIdx.x;
    const int t = threadIdx.x, lane = t & 63, w = t >> 6;
    for (int e = t; e < 768; e += 256) ps[e] = pooled[(size_t)b * E + e];
    __syncthreads();
    float pl[12];
#pragma unroll
    for (int j = 0; j < 12; j++) pl[j] = ps[j * 64 + lane];
    for (int i = 0; i < 10; i++) {
        int o = s * 40 + w * 10 + i;
        const float* wr = hw + (size_t)o * 768;
        float acc = 0.f;
#pragma unroll
        for (int j = 0; j < 12; j++) acc += pl[j] * wr[j * 64 + lane];
        for (int off = 32; off > 0; off >>= 1) acc += __shfl_down(acc, off);
        if (lane == 0) out[(size_t)b * NC + o] = acc + hb[o];
    }
}

// =====================================================================
extern "C" void kernel_launch(void* const* d_in, const int* in_sizes, int n_in,
                              void* d_out, int out_size, void* d_ws, size_t ws_size,
                              hipStream_t stream) {
    const float* x        = (const float*)d_in[0];
    const float* conv_w   = (const float*)d_in[1];
    const float* conv_b   = (const float*)d_in[2];
    const float* cls_tok  = (const float*)d_in[3];
    const float* pos_emb  = (const float*)d_in[4];
    const float* qkv_w    = (const float*)d_in[5];
    const float* qkv_b    = (const float*)d_in[6];
    const float* proj_w   = (const float*)d_in[7];
    const float* proj_b   = (const float*)d_in[8];
    const float* ln1_g    = (const float*)d_in[9];
    const float* ln1_b    = (const float*)d_in[10];
    const float* mlp_w1   = (const float*)d_in[11];
    const float* mlp_b1   = (const float*)d_in[12];
    const float* mlp_w2   = (const float*)d_in[13];
    const float* mlp_b2   = (const float*)d_in[14];
    const float* ln2_g    = (const float*)d_in[15];
    const float* ln2_b    = (const float*)d_in[16];
    const float* hln_g    = (const float*)d_in[17];
    const float* hln_b    = (const float*)d_in[18];
    const float* head_w   = (const float*)d_in[19];
    const float* head_b   = (const float*)d_in[20];
    float* out = (float*)d_out;

    const int M = Bsz * Nn;  // 6304

    // ---- workspace carve-up ----
    char* p = (char*)d_ws;
    __hip_bfloat16* Xb   = (__hip_bfloat16*)p;  p += (size_t)M * E * 2;
    float*          X    = (float*)p;           p += (size_t)M * E * 4;
    __hip_bfloat16* qwb  = (__hip_bfloat16*)p;  p += (size_t)3 * E * E * 2;
    __hip_bfloat16* pwb  = (__hip_bfloat16*)p;  p += (size_t)E * E * 2;
    __hip_bfloat16* w1b  = (__hip_bfloat16*)p;  p += (size_t)FF * E * 2;
    __hip_bfloat16* w2b  = (__hip_bfloat16*)p;  p += (size_t)E * FF * 2;
    __hip_bfloat16* cwb  = (__hip_bfloat16*)p;  p += (size_t)E * E * 2;
    __hip_bfloat16* atth = (__hip_bfloat16*)p;  p += (size_t)M * E * 2;  // head-major [bh][197][96]
    float*          pool = (float*)p;           p += (size_t)Bsz * E * 4;
    char* R = p;
    // live set A (attention): qkvb + Vtg ; live set B (patch/MLP): Hb + Ctmp
    __hip_bfloat16* qkvb = (__hip_bfloat16*)R;
    __hip_bfloat16* Vtg  = (__hip_bfloat16*)(R + 29048832);
    __hip_bfloat16* Hb   = (__hip_bfloat16*)R;
    float*          Ctmp = (float*)(R + 40452096);
    __hip_bfloat16* imb  = (__hip_bfloat16*)R;

    // ---- patch embed ----
    {
        f2b_k<<<(E * E / 4 + 255) / 256, 256, 0, stream>>>(conv_w, cwb, E * E / 4);
        int tot = Bsz * NP * 768;
        im2col_k<<<(tot + 255) / 256, 256, 0, stream>>>(x, imb);
        dim3 g(98, 6);  // M=6272 = 98*64
        gemm_bf16_k<64, 0, 0, 0><<<g, 256, 0, stream>>>(imb, cwb, conv_b, Ctmp, Bsz * NP, E, E);
        int tot2 = Bsz * Nn * E;
        assemble_k<<<(tot2 + 255) / 256, 256, 0, stream>>>(Ctmp, cls_tok, pos_emb, X, Xb);
    }

    const int MB128 = (M + 127) / 128;  // 50
    const int MB64  = (M + 63) / 64;    // 99
    const int cn0 = 3 * E * E / 4, cn1 = E * E / 4, cn2 = FF * E / 4, cn3 = E * FF / 4;
    const int cgrid = (cn0 + cn1 + cn2 + cn3 + 255) / 256;

    // ---- transformer layers ----
    for (int l = 0; l < Lnum; l++) {
        const float* qw = qkv_w + (size_t)l * 3 * E * E;
        const float* qb = qkv_b + (size_t)l * 3 * E;
        const float* pw = proj_w + (size_t)l * E * E;
        const float* pb = proj_b + (size_t)l * E;
        const float* g1 = ln1_g + (size_t)l * E;
        const float* b1 = ln1_b + (size_t)l * E;
        const float* w1 = mlp_w1 + (size_t)l * FF * E;
        const float* bb1 = mlp_b1 + (size_t)l * FF;
        const float* w2 = mlp_w2 + (size_t)l * E * FF;
        const float* bb2 = mlp_b2 + (size_t)l * E;
        const float* g2 = ln2_g + (size_t)l * E;
        const float* b2 = ln2_b + (size_t)l * E;

        f2b4_k<<<cgrid, 256, 0, stream>>>(qw, pw, w1, w2, qwb, pwb, w1b, w2b,
                                          cn0, cn1, cn2, cn3);

        // qkv = Xb @ qwb^T -> bf16 [M, 2304]
        gemm_bf16_k<128, 1, 0, 0><<<dim3(MB128, 18), 256, 0, stream>>>(Xb, qwb, qb, qkvb, M, 3 * E, E);
        // V transpose into Vtg
        vtr_k<<<dim3(4, Bsz * HEADS), 256, 0, stream>>>(qkvb, Vtg);
        // fused attention -> atth (head-major)
        fattn_k<<<Bsz * HEADS, 256, 0, stream>>>(qkvb, Vtg, atth);
        // proj (A head-major) -> f32 Ctmp
        gemm_bf16_k<64, 0, 0, 1><<<dim3(MB64, 6), 256, 0, stream>>>(atth, pwb, pb, Ctmp, M, E, E);
        add_ln_k<<<M, 256, 0, stream>>>(X, Ctmp, g1, b1, Xb);
        // MLP1 + gelu -> bf16 Hb
        gemm_bf16_k<128, 1, 1, 0><<<dim3(MB128, 24), 256, 0, stream>>>(Xb, w1b, bb1, Hb, M, FF, E);
        // MLP2 -> f32 Ctmp
        gemm_bf16_k<64, 0, 0, 0><<<dim3(MB64, 6), 256, 0, stream>>>(Hb, w2b, bb2, Ctmp, M, E, FF);
        add_ln_k<<<M, 256, 0, stream>>>(X, Ctmp, g2, b2, Xb);
    }

    // ---- head ----
    pool_ln_k<<<Bsz, 256, 0, stream>>>(X, hln_g, hln_b, pool);
    head_k<<<dim3(25, Bsz), 256, 0, stream>>>(pool, head_w, head_b, out);
}